// Round 1
// baseline (2186.307 us; speedup 1.0000x reference)
//
#include <hip/hip_runtime.h>

// Problem constants (from reference): N=50000, E=800000, dims 128->128->64->2.
#define IN_DIM 128
#define HID_DIM 128
#define OUT_DIM 64

// ---------------- degree ----------------
__global__ void k_deg(const int* __restrict__ dst, float* __restrict__ deg, int E) {
    int t = blockIdx.x * 256 + threadIdx.x;
    if (t < E) atomicAdd(&deg[dst[t]], 1.0f);
}

__global__ void k_dinv(const float* __restrict__ deg, float* __restrict__ dinv, int N) {
    int t = blockIdx.x * 256 + threadIdx.x;
    if (t < N) dinv[t] = rsqrtf(deg[t] + 1.0f);  // +1 for self-loop
}

// ---------------- GEMM1: xw1 = x @ W1  (K=128, Nout=128) ----------------
// 8 rows/block, 32 threads/row, 4 outputs/thread. Requires N % 8 == 0 (50000 is).
__global__ __launch_bounds__(256) void k_gemm1(const float* __restrict__ x,
                                               const float* __restrict__ W,
                                               float* __restrict__ xw, int N) {
    __shared__ float Ws[IN_DIM * HID_DIM];  // 64 KB
    __shared__ float xs[8][IN_DIM];         // 4 KB
    int tid = threadIdx.x;
    const float4* W4 = (const float4*)W;
    float4* Ws4 = (float4*)Ws;
#pragma unroll
    for (int i = 0; i < 16; ++i) Ws4[tid + 256 * i] = W4[tid + 256 * i];
    int row0 = blockIdx.x * 8;
    const float4* x4 = (const float4*)(x + (size_t)row0 * IN_DIM);
    ((float4*)&xs[0][0])[tid] = x4[tid];
    __syncthreads();
    int ty = tid >> 5, tx = tid & 31;
    float a0 = 0.f, a1 = 0.f, a2 = 0.f, a3 = 0.f;
#pragma unroll 4
    for (int k = 0; k < IN_DIM; ++k) {
        float a = xs[ty][k];
        float4 w = *(const float4*)&Ws[k * HID_DIM + tx * 4];
        a0 += a * w.x; a1 += a * w.y; a2 += a * w.z; a3 += a * w.w;
    }
    float4 r; r.x = a0; r.y = a1; r.z = a2; r.w = a3;
    *(float4*)&xw[(size_t)(row0 + ty) * HID_DIM + tx * 4] = r;
}

// ---------------- GEMM2: xw2 = relu(agg1 + b1) @ W2  (K=128, Nout=64) ----------------
// 16 rows/block, 16 threads/row, 4 outputs/thread. Requires N % 16 == 0 (50000 is).
__global__ __launch_bounds__(256) void k_gemm2(const float* __restrict__ agg1,
                                               const float* __restrict__ b1,
                                               const float* __restrict__ W2,
                                               float* __restrict__ xw2, int N) {
    __shared__ float Ws[IN_DIM * OUT_DIM];  // 32 KB
    __shared__ float xs[16][IN_DIM];        // 8 KB
    __shared__ float b1s[IN_DIM];
    int tid = threadIdx.x;
    const float4* W4 = (const float4*)W2;
    float4* Ws4 = (float4*)Ws;
#pragma unroll
    for (int i = 0; i < 8; ++i) Ws4[tid + 256 * i] = W4[tid + 256 * i];
    if (tid < 32) ((float4*)b1s)[tid] = ((const float4*)b1)[tid];
    __syncthreads();
    int row0 = blockIdx.x * 16;
    const float4* a4 = (const float4*)(agg1 + (size_t)row0 * IN_DIM);
    float4* xs4 = (float4*)&xs[0][0];
#pragma unroll
    for (int i = 0; i < 2; ++i) {
        int q = tid + 256 * i;          // 512 float4 total
        float4 v = a4[q];
        int c4 = q & 31;                // column float4 index (128/4)
        float4 bb = ((float4*)b1s)[c4];
        v.x = fmaxf(v.x + bb.x, 0.f);
        v.y = fmaxf(v.y + bb.y, 0.f);
        v.z = fmaxf(v.z + bb.z, 0.f);
        v.w = fmaxf(v.w + bb.w, 0.f);
        xs4[q] = v;
    }
    __syncthreads();
    int ty = tid >> 4, tx = tid & 15;
    float a0 = 0.f, a1 = 0.f, a2 = 0.f, a3 = 0.f;
#pragma unroll 4
    for (int k = 0; k < IN_DIM; ++k) {
        float a = xs[ty][k];
        float4 w = *(const float4*)&Ws[k * OUT_DIM + tx * 4];
        a0 += a * w.x; a1 += a * w.y; a2 += a * w.z; a3 += a * w.w;
    }
    float4 r; r.x = a0; r.y = a1; r.z = a2; r.w = a3;
    *(float4*)&xw2[(size_t)(row0 + ty) * OUT_DIM + tx * 4] = r;
}

// ---------------- self-loop init: agg = xw * dinv^2 ----------------
// One thread per float4; FSHIFT = log2(F/4).
template <int FSHIFT>
__global__ void k_self(const float* __restrict__ xw, const float* __restrict__ dinv,
                       float* __restrict__ agg, int total4) {
    int t = blockIdx.x * 256 + threadIdx.x;
    if (t >= total4) return;
    int row = t >> FSHIFT;
    float s = dinv[row];
    s *= s;
    float4 v = ((const float4*)xw)[t];
    v.x *= s; v.y *= s; v.z *= s; v.w *= s;
    ((float4*)agg)[t] = v;
}

// ---------------- edge scatter: agg[dst] += xw[src] * dinv[src]*dinv[dst] ----------------
// (F/4) lanes per edge, float4 gather per lane, 4 atomics per lane.
template <int FSHIFT>  // F/4 = 1<<FSHIFT
__global__ void k_edge(const int* __restrict__ src, const int* __restrict__ dst,
                       const float* __restrict__ dinv, const float* __restrict__ xw,
                       float* __restrict__ agg, int E) {
    int t = blockIdx.x * 256 + threadIdx.x;
    int e = t >> FSHIFT;
    if (e >= E) return;
    int c = t & ((1 << FSHIFT) - 1);
    int s = src[e], d = dst[e];
    float nrm = dinv[s] * dinv[d];
    const int F = 4 << FSHIFT;
    float4 v = *(const float4*)(xw + (size_t)s * F + c * 4);
    float* o = agg + (size_t)d * F + c * 4;
    atomicAdd(o + 0, v.x * nrm);
    atomicAdd(o + 1, v.y * nrm);
    atomicAdd(o + 2, v.z * nrm);
    atomicAdd(o + 3, v.w * nrm);
}

// ---------------- final: out = leaky_relu((agg2 + b2) @ Wfc + bfc) ----------------
// 128 rows/block; thread = (row, j) with j in {0,1}.
__global__ __launch_bounds__(256) void k_final(const float* __restrict__ agg2,
                                               const float* __restrict__ b2,
                                               const float* __restrict__ Wfc,
                                               const float* __restrict__ bfc,
                                               float* __restrict__ out, int N) {
    __shared__ float tile[128][68];  // +4 pad keeps float4 alignment, breaks bank stride
    __shared__ float wf[OUT_DIM * 2];
    __shared__ float bf[2];
    int tid = threadIdx.x;
    if (tid < 32) ((float4*)wf)[tid] = ((const float4*)Wfc)[tid];
    if (tid == 32) { bf[0] = bfc[0]; bf[1] = bfc[1]; }
    int row0 = blockIdx.x * 128;
#pragma unroll
    for (int i = 0; i < 8; ++i) {
        int q = tid + 256 * i;          // 2048 float4
        int r = q >> 4, c4 = q & 15;
        int row = row0 + r;
        if (row < N) {
            float4 v = *(const float4*)(agg2 + (size_t)row * OUT_DIM + c4 * 4);
            float4 bb = ((const float4*)b2)[c4];
            v.x += bb.x; v.y += bb.y; v.z += bb.z; v.w += bb.w;
            *(float4*)&tile[r][c4 * 4] = v;
        }
    }
    __syncthreads();
    int i = tid & 127, j = tid >> 7;
    int row = row0 + i;
    if (row < N) {
        float acc = 0.f;
#pragma unroll 8
        for (int k = 0; k < OUT_DIM; ++k) acc += tile[i][k] * wf[k * 2 + j];
        acc += bf[j];
        out[(size_t)row * 2 + j] = acc > 0.f ? acc : 0.01f * acc;
    }
}

extern "C" void kernel_launch(void* const* d_in, const int* in_sizes, int n_in,
                              void* d_out, int out_size, void* d_ws, size_t ws_size,
                              hipStream_t stream) {
    const float* x   = (const float*)d_in[0];
    const int*   ei  = (const int*)d_in[1];
    const float* W1  = (const float*)d_in[2];
    const float* b1  = (const float*)d_in[3];
    const float* W2  = (const float*)d_in[4];
    const float* b2  = (const float*)d_in[5];
    const float* Wfc = (const float*)d_in[6];
    const float* bfc = (const float*)d_in[7];

    const int N = in_sizes[0] / IN_DIM;   // 50000
    const int E = in_sizes[1] / 2;        // 800000
    const int* src = ei;
    const int* dst = ei + E;

    // Workspace layout (floats): deg[N] | dinv[N] | xw1[N*128] | agg1[N*128]
    // xw2 aliases xw1 (dead after edge1); agg2 aliases agg1 (dead after gemm2).
    float* ws   = (float*)d_ws;
    float* deg  = ws;
    float* dinv = ws + N;
    float* xw1  = ws + 2 * (size_t)N;
    float* agg1 = xw1 + (size_t)N * HID_DIM;
    float* xw2  = xw1;
    float* agg2 = agg1;

    hipMemsetAsync(deg, 0, (size_t)N * sizeof(float), stream);

    k_deg<<<(E + 255) / 256, 256, 0, stream>>>(dst, deg, E);
    k_dinv<<<(N + 255) / 256, 256, 0, stream>>>(deg, dinv, N);

    // Layer 1
    k_gemm1<<<N / 8, 256, 0, stream>>>(x, W1, xw1, N);
    k_self<5><<<((N * (HID_DIM / 4)) + 255) / 256, 256, 0, stream>>>(xw1, dinv, agg1, N * (HID_DIM / 4));
    k_edge<5><<<((size_t)E * (HID_DIM / 4) + 255) / 256, 256, 0, stream>>>(src, dst, dinv, xw1, agg1, E);

    // Layer 2 (relu + b1 fused into gemm2 load)
    k_gemm2<<<N / 16, 256, 0, stream>>>(agg1, b1, W2, xw2, N);
    k_self<4><<<((N * (OUT_DIM / 4)) + 255) / 256, 256, 0, stream>>>(xw2, dinv, agg2, N * (OUT_DIM / 4));
    k_edge<4><<<((size_t)E * (OUT_DIM / 4) + 255) / 256, 256, 0, stream>>>(src, dst, dinv, xw2, agg2, E);

    // FC + leaky_relu
    k_final<<<(N + 127) / 128, 256, 0, stream>>>(agg2, b2, Wfc, bfc, (float*)d_out, N);
}

// Round 2
// 446.320 us; speedup vs baseline: 4.8985x; 4.8985x over previous
//
#include <hip/hip_runtime.h>

// Problem constants (from reference): N=50000, E=800000, dims 128->128->64->2.
#define IN_DIM 128
#define HID_DIM 128
#define OUT_DIM 64

// ---------------- degree histogram (int atomics) ----------------
__global__ void k_deg(const int* __restrict__ dst, int* __restrict__ deg, int E) {
    int t = blockIdx.x * 256 + threadIdx.x;
    if (t < E) atomicAdd(&deg[dst[t]], 1);
}

__global__ void k_dinv(const int* __restrict__ deg, float* __restrict__ dinv, int N) {
    int t = blockIdx.x * 256 + threadIdx.x;
    if (t < N) dinv[t] = rsqrtf((float)deg[t] + 1.0f);  // +1 for self-loop
}

// ---------------- exclusive prefix scan over N=50000 (single block) ----------------
__global__ __launch_bounds__(256) void k_scan(const int* __restrict__ deg,
                                              int* __restrict__ row_ptr, int N) {
    __shared__ int part[256];
    int chunk = (N + 255) >> 8;
    int lo = threadIdx.x * chunk;
    int hi = lo + chunk; if (hi > N) hi = N;
    int s = 0;
    for (int i = lo; i < hi; ++i) s += deg[i];
    part[threadIdx.x] = s;
    __syncthreads();
    for (int off = 1; off < 256; off <<= 1) {
        int v = (threadIdx.x >= off) ? part[threadIdx.x - off] : 0;
        __syncthreads();
        part[threadIdx.x] += v;
        __syncthreads();
    }
    int base = part[threadIdx.x] - s;  // exclusive prefix of this chunk
    for (int i = lo; i < hi; ++i) { row_ptr[i] = base; base += deg[i]; }
    if (hi == N && lo < N) row_ptr[N] = base;
}

// ---------------- CSR slot scatter (int atomics on 50k counters) ----------------
__global__ void k_fill(const int* __restrict__ src, const int* __restrict__ dst,
                       const int* __restrict__ row_ptr, int* __restrict__ fill,
                       int* __restrict__ csr_src, int E) {
    int e = blockIdx.x * 256 + threadIdx.x;
    if (e < E) {
        int d = dst[e];
        int slot = row_ptr[d] + atomicAdd(&fill[d], 1);
        csr_src[slot] = src[e];
    }
}

// ---------------- GEMM1: xw1 = x @ W1  (K=128, Nout=128) ----------------
__global__ __launch_bounds__(256) void k_gemm1(const float* __restrict__ x,
                                               const float* __restrict__ W,
                                               float* __restrict__ xw, int N) {
    __shared__ float Ws[IN_DIM * HID_DIM];  // 64 KB
    __shared__ float xs[8][IN_DIM];         // 4 KB
    int tid = threadIdx.x;
    const float4* W4 = (const float4*)W;
    float4* Ws4 = (float4*)Ws;
#pragma unroll
    for (int i = 0; i < 16; ++i) Ws4[tid + 256 * i] = W4[tid + 256 * i];
    int row0 = blockIdx.x * 8;
    const float4* x4 = (const float4*)(x + (size_t)row0 * IN_DIM);
    ((float4*)&xs[0][0])[tid] = x4[tid];
    __syncthreads();
    int ty = tid >> 5, tx = tid & 31;
    float a0 = 0.f, a1 = 0.f, a2 = 0.f, a3 = 0.f;
#pragma unroll 4
    for (int k = 0; k < IN_DIM; ++k) {
        float a = xs[ty][k];
        float4 w = *(const float4*)&Ws[k * HID_DIM + tx * 4];
        a0 += a * w.x; a1 += a * w.y; a2 += a * w.z; a3 += a * w.w;
    }
    float4 r; r.x = a0; r.y = a1; r.z = a2; r.w = a3;
    *(float4*)&xw[(size_t)(row0 + ty) * HID_DIM + tx * 4] = r;
}

// ---------------- GEMM2: xw2 = relu(agg1 + b1) @ W2  (K=128, Nout=64) ----------------
__global__ __launch_bounds__(256) void k_gemm2(const float* __restrict__ agg1,
                                               const float* __restrict__ b1,
                                               const float* __restrict__ W2,
                                               float* __restrict__ xw2, int N) {
    __shared__ float Ws[IN_DIM * OUT_DIM];  // 32 KB
    __shared__ float xs[16][IN_DIM];        // 8 KB
    __shared__ float b1s[IN_DIM];
    int tid = threadIdx.x;
    const float4* W4 = (const float4*)W2;
    float4* Ws4 = (float4*)Ws;
#pragma unroll
    for (int i = 0; i < 8; ++i) Ws4[tid + 256 * i] = W4[tid + 256 * i];
    if (tid < 32) ((float4*)b1s)[tid] = ((const float4*)b1)[tid];
    __syncthreads();
    int row0 = blockIdx.x * 16;
    const float4* a4 = (const float4*)(agg1 + (size_t)row0 * IN_DIM);
    float4* xs4 = (float4*)&xs[0][0];
#pragma unroll
    for (int i = 0; i < 2; ++i) {
        int q = tid + 256 * i;          // 512 float4 total
        float4 v = a4[q];
        int c4 = q & 31;                // column float4 index (128/4)
        float4 bb = ((float4*)b1s)[c4];
        v.x = fmaxf(v.x + bb.x, 0.f);
        v.y = fmaxf(v.y + bb.y, 0.f);
        v.z = fmaxf(v.z + bb.z, 0.f);
        v.w = fmaxf(v.w + bb.w, 0.f);
        xs4[q] = v;
    }
    __syncthreads();
    int ty = tid >> 4, tx = tid & 15;
    float a0 = 0.f, a1 = 0.f, a2 = 0.f, a3 = 0.f;
#pragma unroll 4
    for (int k = 0; k < IN_DIM; ++k) {
        float a = xs[ty][k];
        float4 w = *(const float4*)&Ws[k * OUT_DIM + tx * 4];
        a0 += a * w.x; a1 += a * w.y; a2 += a * w.z; a3 += a * w.w;
    }
    float4 r; r.x = a0; r.y = a1; r.z = a2; r.w = a3;
    *(float4*)&xw2[(size_t)(row0 + ty) * OUT_DIM + tx * 4] = r;
}

// ---------------- CSR aggregation: one wave per dst node, atomic-free ----------------
// agg[d] = dinv[d] * sum_{s in nbr(d)} dinv[s]*xw[s]  +  dinv[d]^2 * xw[d]
template <int F>  // 128 or 64
__global__ __launch_bounds__(256) void k_agg(const int* __restrict__ row_ptr,
                                             const int* __restrict__ csr_src,
                                             const float* __restrict__ dinv,
                                             const float* __restrict__ xw,
                                             float* __restrict__ agg, int N) {
    constexpr int L = F / 4;       // lanes per row: 32 (F=128) or 16 (F=64)
    constexpr int EPW = 64 / L;    // edges in flight per wave: 2 or 4
    int node = (blockIdx.x * 256 + threadIdx.x) >> 6;  // one wave per node
    if (node >= N) return;
    int lane = threadIdx.x & 63;
    int sub = lane / L;            // which edge slot within the wave
    int c   = lane % L;            // float4 column within the row
    int beg = row_ptr[node], end = row_ptr[node + 1];
    float ax = 0.f, ay = 0.f, az = 0.f, aw = 0.f;
    for (int j = beg + sub; j < end; j += EPW) {
        int s = csr_src[j];
        float nrm = dinv[s];
        float4 v = *(const float4*)(xw + (size_t)s * F + c * 4);
        ax += v.x * nrm; ay += v.y * nrm; az += v.z * nrm; aw += v.w * nrm;
    }
    // reduce the EPW sub-accumulators (lanes differing only in 'sub' bits)
#pragma unroll
    for (int off = L; off < 64; off <<= 1) {
        ax += __shfl_xor(ax, off);
        ay += __shfl_xor(ay, off);
        az += __shfl_xor(az, off);
        aw += __shfl_xor(aw, off);
    }
    float dd = dinv[node];
    float4 sv = *(const float4*)(xw + (size_t)node * F + c * 4);
    float s2 = dd * dd;
    float4 r;
    r.x = ax * dd + sv.x * s2;
    r.y = ay * dd + sv.y * s2;
    r.z = az * dd + sv.z * s2;
    r.w = aw * dd + sv.w * s2;
    if (sub == 0) *(float4*)(agg + (size_t)node * F + c * 4) = r;
}

// ---------------- final: out = leaky_relu((agg2 + b2) @ Wfc + bfc) ----------------
__global__ __launch_bounds__(256) void k_final(const float* __restrict__ agg2,
                                               const float* __restrict__ b2,
                                               const float* __restrict__ Wfc,
                                               const float* __restrict__ bfc,
                                               float* __restrict__ out, int N) {
    __shared__ float tile[128][68];
    __shared__ float wf[OUT_DIM * 2];
    __shared__ float bf[2];
    int tid = threadIdx.x;
    if (tid < 32) ((float4*)wf)[tid] = ((const float4*)Wfc)[tid];
    if (tid == 32) { bf[0] = bfc[0]; bf[1] = bfc[1]; }
    int row0 = blockIdx.x * 128;
#pragma unroll
    for (int i = 0; i < 8; ++i) {
        int q = tid + 256 * i;          // 2048 float4
        int r = q >> 4, c4 = q & 15;
        int row = row0 + r;
        if (row < N) {
            float4 v = *(const float4*)(agg2 + (size_t)row * OUT_DIM + c4 * 4);
            float4 bb = ((const float4*)b2)[c4];
            v.x += bb.x; v.y += bb.y; v.z += bb.z; v.w += bb.w;
            *(float4*)&tile[r][c4 * 4] = v;
        }
    }
    __syncthreads();
    int i = tid & 127, j = tid >> 7;
    int row = row0 + i;
    if (row < N) {
        float acc = 0.f;
#pragma unroll 8
        for (int k = 0; k < OUT_DIM; ++k) acc += tile[i][k] * wf[k * 2 + j];
        acc += bf[j];
        out[(size_t)row * 2 + j] = acc > 0.f ? acc : 0.01f * acc;
    }
}

extern "C" void kernel_launch(void* const* d_in, const int* in_sizes, int n_in,
                              void* d_out, int out_size, void* d_ws, size_t ws_size,
                              hipStream_t stream) {
    const float* x   = (const float*)d_in[0];
    const int*   ei  = (const int*)d_in[1];
    const float* W1  = (const float*)d_in[2];
    const float* b1  = (const float*)d_in[3];
    const float* W2  = (const float*)d_in[4];
    const float* b2  = (const float*)d_in[5];
    const float* Wfc = (const float*)d_in[6];
    const float* bfc = (const float*)d_in[7];

    const int N = in_sizes[0] / IN_DIM;   // 50000
    const int E = in_sizes[1] / 2;        // 800000
    const int* src = ei;
    const int* dst = ei + E;

    // Workspace layout:
    // ints:   deg[N] | row_ptr[N+1] | fill[N] | csr_src[E]
    // floats: dinv[N] | xw1[N*128] | agg1[N*128]
    // xw2 aliases xw1 (dead after agg1); agg2 aliases agg1 (dead after gemm2).
    char* wsb = (char*)d_ws;
    int*   deg     = (int*)wsb;                      wsb += (size_t)N * 4;
    int*   row_ptr = (int*)wsb;                      wsb += (size_t)(N + 1) * 4;
    int*   fill    = (int*)wsb;                      wsb += (size_t)N * 4;
    int*   csr_src = (int*)wsb;                      wsb += (size_t)E * 4;
    float* dinv    = (float*)wsb;                    wsb += (size_t)N * 4;
    float* xw1     = (float*)wsb;                    wsb += (size_t)N * HID_DIM * 4;
    float* agg1    = (float*)wsb;
    float* xw2  = xw1;
    float* agg2 = agg1;

    hipMemsetAsync(deg, 0, (size_t)N * sizeof(int), stream);
    hipMemsetAsync(fill, 0, (size_t)N * sizeof(int), stream);

    // CSR build
    k_deg<<<(E + 255) / 256, 256, 0, stream>>>(dst, deg, E);
    k_dinv<<<(N + 255) / 256, 256, 0, stream>>>(deg, dinv, N);
    k_scan<<<1, 256, 0, stream>>>(deg, row_ptr, N);
    k_fill<<<(E + 255) / 256, 256, 0, stream>>>(src, dst, row_ptr, fill, csr_src, E);

    // Layer 1
    k_gemm1<<<N / 8, 256, 0, stream>>>(x, W1, xw1, N);
    k_agg<HID_DIM><<<(N + 3) / 4, 256, 0, stream>>>(row_ptr, csr_src, dinv, xw1, agg1, N);

    // Layer 2 (relu + b1 fused into gemm2 load)
    k_gemm2<<<N / 16, 256, 0, stream>>>(agg1, b1, W2, xw2, N);
    k_agg<OUT_DIM><<<(N + 3) / 4, 256, 0, stream>>>(row_ptr, csr_src, dinv, xw2, agg2, N);

    // FC + leaky_relu
    k_final<<<(N + 127) / 128, 256, 0, stream>>>(agg2, b2, Wfc, bfc, (float*)d_out, N);
}

// Round 3
// 367.142 us; speedup vs baseline: 5.9549x; 1.2157x over previous
//
#include <hip/hip_runtime.h>

// Problem constants (from reference): N=50000, E=800000, dims 128->128->64->2.
#define IN_DIM 128
#define HID_DIM 128
#define OUT_DIM 64

// ---------------- degree histogram (int atomics) ----------------
__global__ void k_deg(const int* __restrict__ dst, int* __restrict__ deg, int E) {
    int t = blockIdx.x * 256 + threadIdx.x;
    if (t < E) atomicAdd(&deg[dst[t]], 1);
}

__global__ void k_dinv(const int* __restrict__ deg, float* __restrict__ dinv, int N) {
    int t = blockIdx.x * 256 + threadIdx.x;
    if (t < N) dinv[t] = rsqrtf((float)deg[t] + 1.0f);  // +1 for self-loop
}

// ---------------- hierarchical exclusive scan (1024 elems/block) ----------------
__global__ __launch_bounds__(256) void k_scan_block(const int* __restrict__ deg,
                                                    int* __restrict__ blk, int N) {
    __shared__ int part[256];
    int t = threadIdx.x;
    int base = blockIdx.x * 1024 + t * 4;
    int s = 0;
    if (base + 3 < N) {
        int4 v = *(const int4*)(deg + base);
        s = v.x + v.y + v.z + v.w;
    } else {
        for (int k = 0; k < 4; ++k) if (base + k < N) s += deg[base + k];
    }
    part[t] = s;
    __syncthreads();
    for (int off = 128; off > 0; off >>= 1) {
        if (t < off) part[t] += part[t + off];
        __syncthreads();
    }
    if (t == 0) blk[blockIdx.x] = part[0];
}

// exclusive scan over nb block sums (nb <= a few thousand), single block w/ carry
__global__ __launch_bounds__(256) void k_scan_sums(int* __restrict__ blk, int nb) {
    __shared__ int part[256];
    int t = threadIdx.x;
    int carry = 0;
    for (int base = 0; base < nb; base += 256) {
        int i = base + t;
        int v = (i < nb) ? blk[i] : 0;
        part[t] = v;
        __syncthreads();
        for (int off = 1; off < 256; off <<= 1) {
            int u = (t >= off) ? part[t - off] : 0;
            __syncthreads();
            part[t] += u;
            __syncthreads();
        }
        if (i < nb) blk[i] = carry + part[t] - v;  // exclusive
        carry += part[255];
        __syncthreads();
    }
}

__global__ __launch_bounds__(256) void k_scan_apply(const int* __restrict__ deg,
                                                    const int* __restrict__ blkoff,
                                                    int* __restrict__ row_ptr, int N) {
    __shared__ int part[256];
    int t = threadIdx.x;
    int base = blockIdx.x * 1024 + t * 4;
    int e0 = 0, e1 = 0, e2 = 0, e3 = 0;
    if (base + 3 < N) {
        int4 v = *(const int4*)(deg + base);
        e0 = v.x; e1 = v.y; e2 = v.z; e3 = v.w;
    } else {
        if (base + 0 < N) e0 = deg[base + 0];
        if (base + 1 < N) e1 = deg[base + 1];
        if (base + 2 < N) e2 = deg[base + 2];
        if (base + 3 < N) e3 = deg[base + 3];
    }
    int s = e0 + e1 + e2 + e3;
    part[t] = s;
    __syncthreads();
    for (int off = 1; off < 256; off <<= 1) {
        int u = (t >= off) ? part[t - off] : 0;
        __syncthreads();
        part[t] += u;
        __syncthreads();
    }
    int excl = part[t] - s + blkoff[blockIdx.x];
    int e[4] = {e0, e1, e2, e3};
#pragma unroll
    for (int k = 0; k < 4; ++k) {
        int g = base + k;
        if (g < N) row_ptr[g] = excl;
        excl += e[k];
        if (g == N - 1) row_ptr[N] = excl;
    }
}

// ---------------- CSR slot scatter (int atomics on 50k counters) ----------------
__global__ void k_fill(const int* __restrict__ src, const int* __restrict__ dst,
                       const int* __restrict__ row_ptr, int* __restrict__ fill,
                       int* __restrict__ csr_src, int E) {
    int e = blockIdx.x * 256 + threadIdx.x;
    if (e < E) {
        int d = dst[e];
        int slot = row_ptr[d] + atomicAdd(&fill[d], 1);
        csr_src[slot] = src[e];
    }
}

// ---------------- GEMM1: xw1 = x @ W1  (K=128, Nout=128) ----------------
__global__ __launch_bounds__(256) void k_gemm1(const float* __restrict__ x,
                                               const float* __restrict__ W,
                                               float* __restrict__ xw, int N) {
    __shared__ float Ws[IN_DIM * HID_DIM];  // 64 KB
    __shared__ float xs[8][IN_DIM];         // 4 KB
    int tid = threadIdx.x;
    const float4* W4 = (const float4*)W;
    float4* Ws4 = (float4*)Ws;
#pragma unroll
    for (int i = 0; i < 16; ++i) Ws4[tid + 256 * i] = W4[tid + 256 * i];
    int row0 = blockIdx.x * 8;
    const float4* x4 = (const float4*)(x + (size_t)row0 * IN_DIM);
    ((float4*)&xs[0][0])[tid] = x4[tid];
    __syncthreads();
    int ty = tid >> 5, tx = tid & 31;
    float a0 = 0.f, a1 = 0.f, a2 = 0.f, a3 = 0.f;
#pragma unroll 4
    for (int k = 0; k < IN_DIM; ++k) {
        float a = xs[ty][k];
        float4 w = *(const float4*)&Ws[k * HID_DIM + tx * 4];
        a0 += a * w.x; a1 += a * w.y; a2 += a * w.z; a3 += a * w.w;
    }
    float4 r; r.x = a0; r.y = a1; r.z = a2; r.w = a3;
    *(float4*)&xw[(size_t)(row0 + ty) * HID_DIM + tx * 4] = r;
}

// ---------------- GEMM2: xw2 = relu(agg1 + b1) @ W2  (K=128, Nout=64) ----------------
__global__ __launch_bounds__(256) void k_gemm2(const float* __restrict__ agg1,
                                               const float* __restrict__ b1,
                                               const float* __restrict__ W2,
                                               float* __restrict__ xw2, int N) {
    __shared__ float Ws[IN_DIM * OUT_DIM];  // 32 KB
    __shared__ float xs[16][IN_DIM];        // 8 KB
    __shared__ float b1s[IN_DIM];
    int tid = threadIdx.x;
    const float4* W4 = (const float4*)W2;
    float4* Ws4 = (float4*)Ws;
#pragma unroll
    for (int i = 0; i < 8; ++i) Ws4[tid + 256 * i] = W4[tid + 256 * i];
    if (tid < 32) ((float4*)b1s)[tid] = ((const float4*)b1)[tid];
    __syncthreads();
    int row0 = blockIdx.x * 16;
    const float4* a4 = (const float4*)(agg1 + (size_t)row0 * IN_DIM);
    float4* xs4 = (float4*)&xs[0][0];
#pragma unroll
    for (int i = 0; i < 2; ++i) {
        int q = tid + 256 * i;          // 512 float4 total
        float4 v = a4[q];
        int c4 = q & 31;                // column float4 index (128/4)
        float4 bb = ((float4*)b1s)[c4];
        v.x = fmaxf(v.x + bb.x, 0.f);
        v.y = fmaxf(v.y + bb.y, 0.f);
        v.z = fmaxf(v.z + bb.z, 0.f);
        v.w = fmaxf(v.w + bb.w, 0.f);
        xs4[q] = v;
    }
    __syncthreads();
    int ty = tid >> 4, tx = tid & 15;
    float a0 = 0.f, a1 = 0.f, a2 = 0.f, a3 = 0.f;
#pragma unroll 4
    for (int k = 0; k < IN_DIM; ++k) {
        float a = xs[ty][k];
        float4 w = *(const float4*)&Ws[k * OUT_DIM + tx * 4];
        a0 += a * w.x; a1 += a * w.y; a2 += a * w.z; a3 += a * w.w;
    }
    float4 r; r.x = a0; r.y = a1; r.z = a2; r.w = a3;
    *(float4*)&xw2[(size_t)(row0 + ty) * OUT_DIM + tx * 4] = r;
}

// ---------------- CSR aggregation: one wave per dst node, atomic-free ----------------
// agg[d] = dinv[d] * sum_{s in nbr(d)} dinv[s]*xw[s]  +  dinv[d]^2 * xw[d]
template <int F>  // 128 or 64
__global__ __launch_bounds__(256) void k_agg(const int* __restrict__ row_ptr,
                                             const int* __restrict__ csr_src,
                                             const float* __restrict__ dinv,
                                             const float* __restrict__ xw,
                                             float* __restrict__ agg, int N) {
    constexpr int L = F / 4;       // lanes per row: 32 (F=128) or 16 (F=64)
    constexpr int EPW = 64 / L;    // edges in flight per wave: 2 or 4
    int node = (blockIdx.x * 256 + threadIdx.x) >> 6;  // one wave per node
    if (node >= N) return;
    int lane = threadIdx.x & 63;
    int sub = lane / L;            // which edge slot within the wave
    int c   = lane % L;            // float4 column within the row
    int beg = row_ptr[node], end = row_ptr[node + 1];
    float ax = 0.f, ay = 0.f, az = 0.f, aw = 0.f;
    for (int j = beg + sub; j < end; j += EPW) {
        int s = csr_src[j];
        float nrm = dinv[s];
        float4 v = *(const float4*)(xw + (size_t)s * F + c * 4);
        ax += v.x * nrm; ay += v.y * nrm; az += v.z * nrm; aw += v.w * nrm;
    }
    // reduce the EPW sub-accumulators (lanes differing only in 'sub' bits)
#pragma unroll
    for (int off = L; off < 64; off <<= 1) {
        ax += __shfl_xor(ax, off);
        ay += __shfl_xor(ay, off);
        az += __shfl_xor(az, off);
        aw += __shfl_xor(aw, off);
    }
    float dd = dinv[node];
    float4 sv = *(const float4*)(xw + (size_t)node * F + c * 4);
    float s2 = dd * dd;
    float4 r;
    r.x = ax * dd + sv.x * s2;
    r.y = ay * dd + sv.y * s2;
    r.z = az * dd + sv.z * s2;
    r.w = aw * dd + sv.w * s2;
    if (sub == 0) *(float4*)(agg + (size_t)node * F + c * 4) = r;
}

// ---------------- final: out = leaky_relu((agg2 + b2) @ Wfc + bfc) ----------------
__global__ __launch_bounds__(256) void k_final(const float* __restrict__ agg2,
                                               const float* __restrict__ b2,
                                               const float* __restrict__ Wfc,
                                               const float* __restrict__ bfc,
                                               float* __restrict__ out, int N) {
    __shared__ float tile[128][68];
    __shared__ float wf[OUT_DIM * 2];
    __shared__ float bf[2];
    int tid = threadIdx.x;
    if (tid < 32) ((float4*)wf)[tid] = ((const float4*)Wfc)[tid];
    if (tid == 32) { bf[0] = bfc[0]; bf[1] = bfc[1]; }
    int row0 = blockIdx.x * 128;
#pragma unroll
    for (int i = 0; i < 8; ++i) {
        int q = tid + 256 * i;          // 2048 float4
        int r = q >> 4, c4 = q & 15;
        int row = row0 + r;
        if (row < N) {
            float4 v = *(const float4*)(agg2 + (size_t)row * OUT_DIM + c4 * 4);
            float4 bb = ((const float4*)b2)[c4];
            v.x += bb.x; v.y += bb.y; v.z += bb.z; v.w += bb.w;
            *(float4*)&tile[r][c4 * 4] = v;
        }
    }
    __syncthreads();
    int i = tid & 127, j = tid >> 7;
    int row = row0 + i;
    if (row < N) {
        float acc = 0.f;
#pragma unroll 8
        for (int k = 0; k < OUT_DIM; ++k) acc += tile[i][k] * wf[k * 2 + j];
        acc += bf[j];
        out[(size_t)row * 2 + j] = acc > 0.f ? acc : 0.01f * acc;
    }
}

extern "C" void kernel_launch(void* const* d_in, const int* in_sizes, int n_in,
                              void* d_out, int out_size, void* d_ws, size_t ws_size,
                              hipStream_t stream) {
    const float* x   = (const float*)d_in[0];
    const int*   ei  = (const int*)d_in[1];
    const float* W1  = (const float*)d_in[2];
    const float* b1  = (const float*)d_in[3];
    const float* W2  = (const float*)d_in[4];
    const float* b2  = (const float*)d_in[5];
    const float* Wfc = (const float*)d_in[6];
    const float* bfc = (const float*)d_in[7];

    const int N = in_sizes[0] / IN_DIM;   // 50000
    const int E = in_sizes[1] / 2;        // 800000
    const int* src = ei;
    const int* dst = ei + E;
    const int nScanBlk = (N + 1023) / 1024;

    // Workspace layout:
    // ints:   deg[N] | row_ptr[N+1] | fill[N] | blk[nScanBlk] | csr_src[E]
    // floats: dinv[N] | xw1[N*128] | agg1[N*128]
    char* wsb = (char*)d_ws;
    int*   deg     = (int*)wsb;                      wsb += (size_t)N * 4;
    int*   row_ptr = (int*)wsb;                      wsb += (size_t)(N + 1) * 4;
    int*   fill    = (int*)wsb;                      wsb += (size_t)N * 4;
    int*   blk     = (int*)wsb;                      wsb += (size_t)((nScanBlk + 3) & ~3) * 4;
    int*   csr_src = (int*)wsb;                      wsb += (size_t)E * 4;
    float* dinv    = (float*)wsb;                    wsb += (size_t)N * 4;
    float* xw1     = (float*)wsb;                    wsb += (size_t)N * HID_DIM * 4;
    float* agg1    = (float*)wsb;
    float* xw2  = xw1;
    float* agg2 = agg1;

    hipMemsetAsync(deg, 0, (size_t)N * sizeof(int), stream);
    hipMemsetAsync(fill, 0, (size_t)N * sizeof(int), stream);

    // CSR build
    k_deg<<<(E + 255) / 256, 256, 0, stream>>>(dst, deg, E);
    k_dinv<<<(N + 255) / 256, 256, 0, stream>>>(deg, dinv, N);
    k_scan_block<<<nScanBlk, 256, 0, stream>>>(deg, blk, N);
    k_scan_sums<<<1, 256, 0, stream>>>(blk, nScanBlk);
    k_scan_apply<<<nScanBlk, 256, 0, stream>>>(deg, blk, row_ptr, N);
    k_fill<<<(E + 255) / 256, 256, 0, stream>>>(src, dst, row_ptr, fill, csr_src, E);

    // Layer 1
    k_gemm1<<<N / 8, 256, 0, stream>>>(x, W1, xw1, N);
    k_agg<HID_DIM><<<(N + 3) / 4, 256, 0, stream>>>(row_ptr, csr_src, dinv, xw1, agg1, N);

    // Layer 2 (relu + b1 fused into gemm2 load)
    k_gemm2<<<N / 16, 256, 0, stream>>>(agg1, b1, W2, xw2, N);
    k_agg<OUT_DIM><<<(N + 3) / 4, 256, 0, stream>>>(row_ptr, csr_src, dinv, xw2, agg2, N);

    // FC + leaky_relu
    k_final<<<(N + 127) / 128, 256, 0, stream>>>(agg2, b2, Wfc, bfc, (float*)d_out, N);
}

// Round 4
// 294.574 us; speedup vs baseline: 7.4219x; 1.2464x over previous
//
#include <hip/hip_runtime.h>
#include <hip/hip_fp16.h>

// Problem constants (from reference): N=50000, E=800000, dims 128->128->64->2.
#define IN_DIM 128
#define HID_DIM 128
#define OUT_DIM 64

// ---------------- degree histogram (int atomics) ----------------
__global__ void k_deg(const int* __restrict__ dst, int* __restrict__ deg, int E) {
    int t = blockIdx.x * 256 + threadIdx.x;
    if (t < E) atomicAdd(&deg[dst[t]], 1);
}

__global__ void k_dinv(const int* __restrict__ deg, float* __restrict__ dinv, int N) {
    int t = blockIdx.x * 256 + threadIdx.x;
    if (t < N) dinv[t] = rsqrtf((float)deg[t] + 1.0f);  // +1 for self-loop
}

// ---------------- hierarchical exclusive scan (1024 elems/block) ----------------
__global__ __launch_bounds__(256) void k_scan_block(const int* __restrict__ deg,
                                                    int* __restrict__ blk, int N) {
    __shared__ int part[256];
    int t = threadIdx.x;
    int base = blockIdx.x * 1024 + t * 4;
    int s = 0;
    if (base + 3 < N) {
        int4 v = *(const int4*)(deg + base);
        s = v.x + v.y + v.z + v.w;
    } else {
        for (int k = 0; k < 4; ++k) if (base + k < N) s += deg[base + k];
    }
    part[t] = s;
    __syncthreads();
    for (int off = 128; off > 0; off >>= 1) {
        if (t < off) part[t] += part[t + off];
        __syncthreads();
    }
    if (t == 0) blk[blockIdx.x] = part[0];
}

__global__ __launch_bounds__(256) void k_scan_sums(int* __restrict__ blk, int nb) {
    __shared__ int part[256];
    int t = threadIdx.x;
    int carry = 0;
    for (int base = 0; base < nb; base += 256) {
        int i = base + t;
        int v = (i < nb) ? blk[i] : 0;
        part[t] = v;
        __syncthreads();
        for (int off = 1; off < 256; off <<= 1) {
            int u = (t >= off) ? part[t - off] : 0;
            __syncthreads();
            part[t] += u;
            __syncthreads();
        }
        if (i < nb) blk[i] = carry + part[t] - v;  // exclusive
        carry += part[255];
        __syncthreads();
    }
}

__global__ __launch_bounds__(256) void k_scan_apply(const int* __restrict__ deg,
                                                    const int* __restrict__ blkoff,
                                                    int* __restrict__ row_ptr, int N) {
    __shared__ int part[256];
    int t = threadIdx.x;
    int base = blockIdx.x * 1024 + t * 4;
    int e0 = 0, e1 = 0, e2 = 0, e3 = 0;
    if (base + 3 < N) {
        int4 v = *(const int4*)(deg + base);
        e0 = v.x; e1 = v.y; e2 = v.z; e3 = v.w;
    } else {
        if (base + 0 < N) e0 = deg[base + 0];
        if (base + 1 < N) e1 = deg[base + 1];
        if (base + 2 < N) e2 = deg[base + 2];
        if (base + 3 < N) e3 = deg[base + 3];
    }
    int s = e0 + e1 + e2 + e3;
    part[t] = s;
    __syncthreads();
    for (int off = 1; off < 256; off <<= 1) {
        int u = (t >= off) ? part[t - off] : 0;
        __syncthreads();
        part[t] += u;
        __syncthreads();
    }
    int excl = part[t] - s + blkoff[blockIdx.x];
    int e[4] = {e0, e1, e2, e3};
#pragma unroll
    for (int k = 0; k < 4; ++k) {
        int g = base + k;
        if (g < N) row_ptr[g] = excl;
        excl += e[k];
        if (g == N - 1) row_ptr[N] = excl;
    }
}

// ---------------- CSR slot scatter (int atomics on 50k counters) ----------------
__global__ void k_fill(const int* __restrict__ src, const int* __restrict__ dst,
                       const int* __restrict__ row_ptr, int* __restrict__ fill,
                       int* __restrict__ csr_src, int E) {
    int e = blockIdx.x * 256 + threadIdx.x;
    if (e < E) {
        int d = dst[e];
        int slot = row_ptr[d] + atomicAdd(&fill[d], 1);
        csr_src[slot] = src[e];
    }
}

// ---------------- GEMM1: xw1h = fp16(x @ W1)  (K=128, 128 cols) ----------------
// Block tile 128x128, 256 threads, 8 rows x 8 cols per thread.
// Rows: ty + 16j (conflict-free b128 A-reads); cols: {4tx, 64+4tx}.
__global__ __launch_bounds__(256) void k_gemm1(const float* __restrict__ x,
                                               const float* __restrict__ W,
                                               __half* __restrict__ xwh, int N) {
    __shared__ float xs[128][132];   // [row][k], pad 4 keeps 16B align of rows
    __shared__ float Ws[128][128];   // [k][col]
    int tid = threadIdx.x;
    const float4* W4 = (const float4*)W;
    float4* Ws4 = (float4*)&Ws[0][0];
#pragma unroll
    for (int i = 0; i < 16; ++i) Ws4[tid + 256 * i] = W4[tid + 256 * i];
    int row0 = blockIdx.x * 128;
#pragma unroll
    for (int i = 0; i < 16; ++i) {
        int q = tid + 256 * i;              // 4096 float4
        int r = q >> 5, c4 = q & 31;
        int row = row0 + r; if (row > N - 1) row = N - 1;
        *(float4*)&xs[r][c4 * 4] = *(const float4*)(x + (size_t)row * IN_DIM + c4 * 4);
    }
    __syncthreads();
    int tx = tid & 15, ty = tid >> 4;
    float4 aclo[8], achi[8];
#pragma unroll
    for (int j = 0; j < 8; ++j) {
        aclo[j] = make_float4(0.f, 0.f, 0.f, 0.f);
        achi[j] = make_float4(0.f, 0.f, 0.f, 0.f);
    }
#pragma unroll 2
    for (int k4 = 0; k4 < 32; ++k4) {
        float4 av[8];
#pragma unroll
        for (int j = 0; j < 8; ++j) av[j] = *(const float4*)&xs[ty + 16 * j][k4 * 4];
#pragma unroll
        for (int kk = 0; kk < 4; ++kk) {
            float4 blo = *(const float4*)&Ws[k4 * 4 + kk][4 * tx];
            float4 bhi = *(const float4*)&Ws[k4 * 4 + kk][64 + 4 * tx];
#pragma unroll
            for (int j = 0; j < 8; ++j) {
                float a = (kk == 0) ? av[j].x : (kk == 1) ? av[j].y : (kk == 2) ? av[j].z : av[j].w;
                aclo[j].x += a * blo.x; aclo[j].y += a * blo.y;
                aclo[j].z += a * blo.z; aclo[j].w += a * blo.w;
                achi[j].x += a * bhi.x; achi[j].y += a * bhi.y;
                achi[j].z += a * bhi.z; achi[j].w += a * bhi.w;
            }
        }
    }
#pragma unroll
    for (int j = 0; j < 8; ++j) {
        int row = row0 + ty + 16 * j;
        if (row < N) {
            union { __half2 h[2]; uint2 u; } lo, hi;
            lo.h[0] = __floats2half2_rn(aclo[j].x, aclo[j].y);
            lo.h[1] = __floats2half2_rn(aclo[j].z, aclo[j].w);
            hi.h[0] = __floats2half2_rn(achi[j].x, achi[j].y);
            hi.h[1] = __floats2half2_rn(achi[j].z, achi[j].w);
            uint2* p = (uint2*)(xwh + (size_t)row * HID_DIM);
            p[tx] = lo.u;
            p[16 + tx] = hi.u;
        }
    }
}

// ---------------- GEMM2: xw2h = fp16(relu(agg1 + b1) @ W2)  (K=128, 64 cols) ----------------
// Block tile 128x64, 256 threads, 4 rows x 8 cols per thread.
// Rows: ty + 32j; cols: {4tx, 32+4tx}.
__global__ __launch_bounds__(256) void k_gemm2(const float* __restrict__ agg1,
                                               const float* __restrict__ b1,
                                               const float* __restrict__ W2,
                                               __half* __restrict__ xw2h, int N) {
    __shared__ float xs[128][132];
    __shared__ float Ws[128][OUT_DIM];
    __shared__ float b1s[HID_DIM];
    int tid = threadIdx.x;
    if (tid < 32) ((float4*)b1s)[tid] = ((const float4*)b1)[tid];
    const float4* W4 = (const float4*)W2;
    float4* Ws4 = (float4*)&Ws[0][0];
#pragma unroll
    for (int i = 0; i < 8; ++i) Ws4[tid + 256 * i] = W4[tid + 256 * i];
    __syncthreads();
    int row0 = blockIdx.x * 128;
#pragma unroll
    for (int i = 0; i < 16; ++i) {
        int q = tid + 256 * i;
        int r = q >> 5, c4 = q & 31;
        int row = row0 + r; if (row > N - 1) row = N - 1;
        float4 v = *(const float4*)(agg1 + (size_t)row * HID_DIM + c4 * 4);
        float4 bb = ((float4*)b1s)[c4];
        v.x = fmaxf(v.x + bb.x, 0.f);
        v.y = fmaxf(v.y + bb.y, 0.f);
        v.z = fmaxf(v.z + bb.z, 0.f);
        v.w = fmaxf(v.w + bb.w, 0.f);
        *(float4*)&xs[r][c4 * 4] = v;
    }
    __syncthreads();
    int tx = tid & 7, ty = tid >> 3;
    float4 aclo[4], achi[4];
#pragma unroll
    for (int j = 0; j < 4; ++j) {
        aclo[j] = make_float4(0.f, 0.f, 0.f, 0.f);
        achi[j] = make_float4(0.f, 0.f, 0.f, 0.f);
    }
#pragma unroll 2
    for (int k4 = 0; k4 < 32; ++k4) {
        float4 av[4];
#pragma unroll
        for (int j = 0; j < 4; ++j) av[j] = *(const float4*)&xs[ty + 32 * j][k4 * 4];
#pragma unroll
        for (int kk = 0; kk < 4; ++kk) {
            float4 blo = *(const float4*)&Ws[k4 * 4 + kk][4 * tx];
            float4 bhi = *(const float4*)&Ws[k4 * 4 + kk][32 + 4 * tx];
#pragma unroll
            for (int j = 0; j < 4; ++j) {
                float a = (kk == 0) ? av[j].x : (kk == 1) ? av[j].y : (kk == 2) ? av[j].z : av[j].w;
                aclo[j].x += a * blo.x; aclo[j].y += a * blo.y;
                aclo[j].z += a * blo.z; aclo[j].w += a * blo.w;
                achi[j].x += a * bhi.x; achi[j].y += a * bhi.y;
                achi[j].z += a * bhi.z; achi[j].w += a * bhi.w;
            }
        }
    }
#pragma unroll
    for (int j = 0; j < 4; ++j) {
        int row = row0 + ty + 32 * j;
        if (row < N) {
            union { __half2 h[2]; uint2 u; } lo, hi;
            lo.h[0] = __floats2half2_rn(aclo[j].x, aclo[j].y);
            lo.h[1] = __floats2half2_rn(aclo[j].z, aclo[j].w);
            hi.h[0] = __floats2half2_rn(achi[j].x, achi[j].y);
            hi.h[1] = __floats2half2_rn(achi[j].z, achi[j].w);
            uint2* p = (uint2*)(xw2h + (size_t)row * OUT_DIM);
            p[tx] = lo.u;
            p[8 + tx] = hi.u;
        }
    }
}

// ---------------- CSR aggregation (fp16 gather): one wave per dst node ----------------
// agg[d] = dinv[d] * sum_{s in nbr(d)} dinv[s]*xw[s]  +  dinv[d]^2 * xw[d]
template <int F>  // 128 or 64
__global__ __launch_bounds__(256) void k_agg(const int* __restrict__ row_ptr,
                                             const int* __restrict__ csr_src,
                                             const float* __restrict__ dinv,
                                             const __half* __restrict__ xwh,
                                             float* __restrict__ agg, int N) {
    constexpr int L = F / 8;       // lanes per row: 16 (F=128) or 8 (F=64), 16B/lane
    constexpr int EPW = 64 / L;    // edges in flight per wave: 4 or 8
    int node = (blockIdx.x * 256 + threadIdx.x) >> 6;  // one wave per node
    if (node >= N) return;
    int lane = threadIdx.x & 63;
    int sub = lane / L;
    int c   = lane % L;            // 8-half chunk index
    int beg = row_ptr[node], end = row_ptr[node + 1];
    float a0 = 0.f, a1 = 0.f, a2 = 0.f, a3 = 0.f;
    float a4 = 0.f, a5 = 0.f, a6 = 0.f, a7 = 0.f;
    for (int j = beg + sub; j < end; j += EPW) {
        int s = csr_src[j];
        float nrm = dinv[s];
        uint4 u = *(const uint4*)(xwh + (size_t)s * F + c * 8);
        float2 v0 = __half22float2(*(__half2*)&u.x);
        float2 v1 = __half22float2(*(__half2*)&u.y);
        float2 v2 = __half22float2(*(__half2*)&u.z);
        float2 v3 = __half22float2(*(__half2*)&u.w);
        a0 += v0.x * nrm; a1 += v0.y * nrm;
        a2 += v1.x * nrm; a3 += v1.y * nrm;
        a4 += v2.x * nrm; a5 += v2.y * nrm;
        a6 += v3.x * nrm; a7 += v3.y * nrm;
    }
#pragma unroll
    for (int off = L; off < 64; off <<= 1) {
        a0 += __shfl_xor(a0, off); a1 += __shfl_xor(a1, off);
        a2 += __shfl_xor(a2, off); a3 += __shfl_xor(a3, off);
        a4 += __shfl_xor(a4, off); a5 += __shfl_xor(a5, off);
        a6 += __shfl_xor(a6, off); a7 += __shfl_xor(a7, off);
    }
    float dd = dinv[node];
    float s2 = dd * dd;
    uint4 u = *(const uint4*)(xwh + (size_t)node * F + c * 8);
    float2 v0 = __half22float2(*(__half2*)&u.x);
    float2 v1 = __half22float2(*(__half2*)&u.y);
    float2 v2 = __half22float2(*(__half2*)&u.z);
    float2 v3 = __half22float2(*(__half2*)&u.w);
    if (sub == 0) {
        float4 r0, r1;
        r0.x = a0 * dd + v0.x * s2; r0.y = a1 * dd + v0.y * s2;
        r0.z = a2 * dd + v1.x * s2; r0.w = a3 * dd + v1.y * s2;
        r1.x = a4 * dd + v2.x * s2; r1.y = a5 * dd + v2.y * s2;
        r1.z = a6 * dd + v3.x * s2; r1.w = a7 * dd + v3.y * s2;
        float* o = agg + (size_t)node * F + c * 8;
        *(float4*)o = r0;
        *(float4*)(o + 4) = r1;
    }
}

// ---------------- final: out = leaky_relu((agg2 + b2) @ Wfc + bfc) ----------------
__global__ __launch_bounds__(256) void k_final(const float* __restrict__ agg2,
                                               const float* __restrict__ b2,
                                               const float* __restrict__ Wfc,
                                               const float* __restrict__ bfc,
                                               float* __restrict__ out, int N) {
    __shared__ float tile[128][68];
    __shared__ float wf[OUT_DIM * 2];
    __shared__ float bf[2];
    int tid = threadIdx.x;
    if (tid < 32) ((float4*)wf)[tid] = ((const float4*)Wfc)[tid];
    if (tid == 32) { bf[0] = bfc[0]; bf[1] = bfc[1]; }
    int row0 = blockIdx.x * 128;
#pragma unroll
    for (int i = 0; i < 8; ++i) {
        int q = tid + 256 * i;          // 2048 float4
        int r = q >> 4, c4 = q & 15;
        int row = row0 + r;
        if (row < N) {
            float4 v = *(const float4*)(agg2 + (size_t)row * OUT_DIM + c4 * 4);
            float4 bb = ((const float4*)b2)[c4];
            v.x += bb.x; v.y += bb.y; v.z += bb.z; v.w += bb.w;
            *(float4*)&tile[r][c4 * 4] = v;
        }
    }
    __syncthreads();
    int i = tid & 127, j = tid >> 7;
    int row = row0 + i;
    if (row < N) {
        float acc = 0.f;
#pragma unroll 8
        for (int k = 0; k < OUT_DIM; ++k) acc += tile[i][k] * wf[k * 2 + j];
        acc += bf[j];
        out[(size_t)row * 2 + j] = acc > 0.f ? acc : 0.01f * acc;
    }
}

extern "C" void kernel_launch(void* const* d_in, const int* in_sizes, int n_in,
                              void* d_out, int out_size, void* d_ws, size_t ws_size,
                              hipStream_t stream) {
    const float* x   = (const float*)d_in[0];
    const int*   ei  = (const int*)d_in[1];
    const float* W1  = (const float*)d_in[2];
    const float* b1  = (const float*)d_in[3];
    const float* W2  = (const float*)d_in[4];
    const float* b2  = (const float*)d_in[5];
    const float* Wfc = (const float*)d_in[6];
    const float* bfc = (const float*)d_in[7];

    const int N = in_sizes[0] / IN_DIM;   // 50000
    const int E = in_sizes[1] / 2;        // 800000
    const int* src = ei;
    const int* dst = ei + E;
    const int nScanBlk = (N + 1023) / 1024;

    // Workspace layout (each region 256B-aligned):
    // deg[N] row_ptr[N+1] fill[N] blk[] csr_src[E] (int) | dinv[N] agg1[N*128] (f32) | xw1h[N*128] (f16)
    // xw2h aliases xw1h; agg2 aliases agg1.
    char* base = (char*)d_ws;
    size_t off = 0;
    auto take = [&](size_t bytes) { size_t o = off; off = (off + bytes + 255) & ~(size_t)255; return (void*)(base + o); };
    int*    deg     = (int*)take((size_t)N * 4);
    int*    row_ptr = (int*)take((size_t)(N + 1) * 4);
    int*    fill    = (int*)take((size_t)N * 4);
    int*    blk     = (int*)take((size_t)nScanBlk * 4);
    int*    csr_src = (int*)take((size_t)E * 4);
    float*  dinv    = (float*)take((size_t)N * 4);
    float*  agg1    = (float*)take((size_t)N * HID_DIM * 4);
    __half* xw1h    = (__half*)take((size_t)N * HID_DIM * 2);
    __half* xw2h    = xw1h;
    float*  agg2    = agg1;

    hipMemsetAsync(deg, 0, (size_t)N * sizeof(int), stream);
    hipMemsetAsync(fill, 0, (size_t)N * sizeof(int), stream);

    // CSR build
    k_deg<<<(E + 255) / 256, 256, 0, stream>>>(dst, deg, E);
    k_dinv<<<(N + 255) / 256, 256, 0, stream>>>(deg, dinv, N);
    k_scan_block<<<nScanBlk, 256, 0, stream>>>(deg, blk, N);
    k_scan_sums<<<1, 256, 0, stream>>>(blk, nScanBlk);
    k_scan_apply<<<nScanBlk, 256, 0, stream>>>(deg, blk, row_ptr, N);
    k_fill<<<(E + 255) / 256, 256, 0, stream>>>(src, dst, row_ptr, fill, csr_src, E);

    const int nTile = (N + 127) / 128;

    // Layer 1
    k_gemm1<<<nTile, 256, 0, stream>>>(x, W1, xw1h, N);
    k_agg<HID_DIM><<<(N + 3) / 4, 256, 0, stream>>>(row_ptr, csr_src, dinv, xw1h, agg1, N);

    // Layer 2 (relu + b1 fused into gemm2 staging)
    k_gemm2<<<nTile, 256, 0, stream>>>(agg1, b1, W2, xw2h, N);
    k_agg<OUT_DIM><<<(N + 3) / 4, 256, 0, stream>>>(row_ptr, csr_src, dinv, xw2h, agg2, N);

    // FC + leaky_relu
    k_final<<<(N + 127) / 128, 256, 0, stream>>>(agg2, b2, Wfc, bfc, (float*)d_out, N);
}

// Round 5
// 227.235 us; speedup vs baseline: 9.6214x; 1.2963x over previous
//
#include <hip/hip_runtime.h>
#include <hip/hip_fp16.h>

// Problem constants (from reference): N=50000, E=800000, dims 128->128->64->2.
#define IN_DIM 128
#define HID_DIM 128
#define OUT_DIM 64
#define BINW 128          // nodes per bin (dst >> 7)
#define BINSHIFT 7
#define MAXBIN 512        // LDS capacity bound; nbin = ceil(N/128) = 391 for N=50000
#define EBLK 256          // blocks in edge passes

// ---------------- P1: per-block bin histogram ----------------
__global__ __launch_bounds__(256) void k_bin_hist(const int* __restrict__ dst,
                                                  int* __restrict__ hist, int E, int nbin) {
    __shared__ int h[MAXBIN];
    int tid = threadIdx.x;
    for (int k = tid; k < nbin; k += 256) h[k] = 0;
    __syncthreads();
    int per = E / gridDim.x;
    int base = blockIdx.x * per;
    int end = (blockIdx.x + 1 == gridDim.x) ? E : base + per;
    for (int i = base + tid; i < end; i += 256)
        atomicAdd(&h[dst[i] >> BINSHIFT], 1);
    __syncthreads();
    for (int k = tid; k < nbin; k += 256) hist[k * EBLK + blockIdx.x] = h[k];
}

// ---------------- P2a: scan each bin's 256 per-block counts ----------------
__global__ __launch_bounds__(256) void k_bin_scan(int* __restrict__ hist,
                                                  int* __restrict__ total) {
    __shared__ int part[256];
    int k = blockIdx.x;
    int t = threadIdx.x;
    int v = hist[k * EBLK + t];
    part[t] = v;
    __syncthreads();
    for (int off = 1; off < 256; off <<= 1) {
        int u = (t >= off) ? part[t - off] : 0;
        __syncthreads();
        part[t] += u;
        __syncthreads();
    }
    hist[k * EBLK + t] = part[t] - v;  // exclusive within bin
    if (t == 255) total[k] = part[255];
}

// ---------------- P2b: exclusive scan of bin totals ----------------
__global__ __launch_bounds__(256) void k_bin_base(const int* __restrict__ total,
                                                  int* __restrict__ bin_base, int nbin) {
    __shared__ int part[256];
    int t = threadIdx.x;
    int carry = 0;
    for (int base = 0; base < nbin; base += 256) {
        int i = base + t;
        int v = (i < nbin) ? total[i] : 0;
        part[t] = v;
        __syncthreads();
        for (int off = 1; off < 256; off <<= 1) {
            int u = (t >= off) ? part[t - off] : 0;
            __syncthreads();
            part[t] += u;
            __syncthreads();
        }
        if (i < nbin) bin_base[i] = carry + part[t] - v;
        carry += part[255];
        __syncthreads();
    }
    if (t == 0) bin_base[nbin] = carry;  // == E
}

// ---------------- P3: scatter packed edges into bin segments ----------------
__global__ __launch_bounds__(256) void k_bin_scatter(const int* __restrict__ src,
                                                     const int* __restrict__ dst,
                                                     const int* __restrict__ hist,
                                                     const int* __restrict__ bin_base,
                                                     unsigned int* __restrict__ ebin,
                                                     int E, int nbin) {
    __shared__ int off[MAXBIN];
    int tid = threadIdx.x;
    for (int k = tid; k < nbin; k += 256)
        off[k] = bin_base[k] + hist[k * EBLK + blockIdx.x];
    __syncthreads();
    int per = E / gridDim.x;
    int base = blockIdx.x * per;
    int end = (blockIdx.x + 1 == gridDim.x) ? E : base + per;
    for (int i = base + tid; i < end; i += 256) {
        unsigned int s = (unsigned int)src[i];
        unsigned int d = (unsigned int)dst[i];
        int pos = atomicAdd(&off[d >> BINSHIFT], 1);
        ebin[pos] = s | (d << 16);
    }
}

// ---------------- P4: per-bin fine fill — row_ptr, dinv, csr_src ----------------
// One block owns one bin: all csr_src writes land in its private segment.
__global__ __launch_bounds__(256) void k_bin_fill(const unsigned int* __restrict__ ebin,
                                                  const int* __restrict__ bin_base,
                                                  int* __restrict__ row_ptr,
                                                  int* __restrict__ csr_src,
                                                  float* __restrict__ dinv, int N, int nbin) {
    __shared__ int cnt[BINW];
    __shared__ int excl[BINW];
    __shared__ int start[BINW];
    int k = blockIdx.x;
    int node0 = k * BINW;
    int nn = min(BINW, N - node0);
    int t = threadIdx.x;
    if (t < BINW) cnt[t] = 0;
    __syncthreads();
    int eb = bin_base[k], ee = bin_base[k + 1];
    for (int i = eb + t; i < ee; i += 256)
        atomicAdd(&cnt[(ebin[i] >> 16) - node0], 1);
    __syncthreads();
    if (t < BINW) excl[t] = (t < nn) ? cnt[t] : 0;
    __syncthreads();
    for (int off = 1; off < BINW; off <<= 1) {
        int u = 0;
        if (t < BINW && t >= off) u = excl[t - off];
        __syncthreads();
        if (t < BINW) excl[t] += u;   // inclusive scan
        __syncthreads();
    }
    if (t < nn) {
        int deg = cnt[t];
        int e0 = eb + excl[t] - deg;  // exclusive
        start[t] = e0;
        row_ptr[node0 + t] = e0;
        dinv[node0 + t] = rsqrtf((float)deg + 1.0f);
        cnt[t] = 0;                   // reuse as fill counter
    }
    if (k == nbin - 1 && t == 0) row_ptr[N] = ee;
    __syncthreads();
    for (int i = eb + t; i < ee; i += 256) {
        unsigned int e = ebin[i];
        int s = (int)(e & 0xffffu);
        int dl = (int)(e >> 16) - node0;
        int slot = start[dl] + atomicAdd(&cnt[dl], 1);
        csr_src[slot] = s;
    }
}

// ---------------- GEMM1: xw1h = fp16(x @ W1)  (K=128, 128 cols) ----------------
__global__ __launch_bounds__(256) void k_gemm1(const float* __restrict__ x,
                                               const float* __restrict__ W,
                                               __half* __restrict__ xwh, int N) {
    __shared__ float xs[128][132];   // [row][k], pad 4 keeps 16B align of rows
    __shared__ float Ws[128][128];   // [k][col]
    int tid = threadIdx.x;
    const float4* W4 = (const float4*)W;
    float4* Ws4 = (float4*)&Ws[0][0];
#pragma unroll
    for (int i = 0; i < 16; ++i) Ws4[tid + 256 * i] = W4[tid + 256 * i];
    int row0 = blockIdx.x * 128;
#pragma unroll
    for (int i = 0; i < 16; ++i) {
        int q = tid + 256 * i;              // 4096 float4
        int r = q >> 5, c4 = q & 31;
        int row = row0 + r; if (row > N - 1) row = N - 1;
        *(float4*)&xs[r][c4 * 4] = *(const float4*)(x + (size_t)row * IN_DIM + c4 * 4);
    }
    __syncthreads();
    int tx = tid & 15, ty = tid >> 4;
    float4 aclo[8], achi[8];
#pragma unroll
    for (int j = 0; j < 8; ++j) {
        aclo[j] = make_float4(0.f, 0.f, 0.f, 0.f);
        achi[j] = make_float4(0.f, 0.f, 0.f, 0.f);
    }
#pragma unroll 2
    for (int k4 = 0; k4 < 32; ++k4) {
        float4 av[8];
#pragma unroll
        for (int j = 0; j < 8; ++j) av[j] = *(const float4*)&xs[ty + 16 * j][k4 * 4];
#pragma unroll
        for (int kk = 0; kk < 4; ++kk) {
            float4 blo = *(const float4*)&Ws[k4 * 4 + kk][4 * tx];
            float4 bhi = *(const float4*)&Ws[k4 * 4 + kk][64 + 4 * tx];
#pragma unroll
            for (int j = 0; j < 8; ++j) {
                float a = (kk == 0) ? av[j].x : (kk == 1) ? av[j].y : (kk == 2) ? av[j].z : av[j].w;
                aclo[j].x += a * blo.x; aclo[j].y += a * blo.y;
                aclo[j].z += a * blo.z; aclo[j].w += a * blo.w;
                achi[j].x += a * bhi.x; achi[j].y += a * bhi.y;
                achi[j].z += a * bhi.z; achi[j].w += a * bhi.w;
            }
        }
    }
#pragma unroll
    for (int j = 0; j < 8; ++j) {
        int row = row0 + ty + 16 * j;
        if (row < N) {
            union { __half2 h[2]; uint2 u; } lo, hi;
            lo.h[0] = __floats2half2_rn(aclo[j].x, aclo[j].y);
            lo.h[1] = __floats2half2_rn(aclo[j].z, aclo[j].w);
            hi.h[0] = __floats2half2_rn(achi[j].x, achi[j].y);
            hi.h[1] = __floats2half2_rn(achi[j].z, achi[j].w);
            uint2* p = (uint2*)(xwh + (size_t)row * HID_DIM);
            p[tx] = lo.u;
            p[16 + tx] = hi.u;
        }
    }
}

// ---------------- GEMM2: xw2h = fp16(relu(agg1 + b1) @ W2)  (K=128, 64 cols) ----------------
__global__ __launch_bounds__(256) void k_gemm2(const float* __restrict__ agg1,
                                               const float* __restrict__ b1,
                                               const float* __restrict__ W2,
                                               __half* __restrict__ xw2h, int N) {
    __shared__ float xs[128][132];
    __shared__ float Ws[128][OUT_DIM];
    __shared__ float b1s[HID_DIM];
    int tid = threadIdx.x;
    if (tid < 32) ((float4*)b1s)[tid] = ((const float4*)b1)[tid];
    const float4* W4 = (const float4*)W2;
    float4* Ws4 = (float4*)&Ws[0][0];
#pragma unroll
    for (int i = 0; i < 8; ++i) Ws4[tid + 256 * i] = W4[tid + 256 * i];
    __syncthreads();
    int row0 = blockIdx.x * 128;
#pragma unroll
    for (int i = 0; i < 16; ++i) {
        int q = tid + 256 * i;
        int r = q >> 5, c4 = q & 31;
        int row = row0 + r; if (row > N - 1) row = N - 1;
        float4 v = *(const float4*)(agg1 + (size_t)row * HID_DIM + c4 * 4);
        float4 bb = ((float4*)b1s)[c4];
        v.x = fmaxf(v.x + bb.x, 0.f);
        v.y = fmaxf(v.y + bb.y, 0.f);
        v.z = fmaxf(v.z + bb.z, 0.f);
        v.w = fmaxf(v.w + bb.w, 0.f);
        *(float4*)&xs[r][c4 * 4] = v;
    }
    __syncthreads();
    int tx = tid & 7, ty = tid >> 3;
    float4 aclo[4], achi[4];
#pragma unroll
    for (int j = 0; j < 4; ++j) {
        aclo[j] = make_float4(0.f, 0.f, 0.f, 0.f);
        achi[j] = make_float4(0.f, 0.f, 0.f, 0.f);
    }
#pragma unroll 2
    for (int k4 = 0; k4 < 32; ++k4) {
        float4 av[4];
#pragma unroll
        for (int j = 0; j < 4; ++j) av[j] = *(const float4*)&xs[ty + 32 * j][k4 * 4];
#pragma unroll
        for (int kk = 0; kk < 4; ++kk) {
            float4 blo = *(const float4*)&Ws[k4 * 4 + kk][4 * tx];
            float4 bhi = *(const float4*)&Ws[k4 * 4 + kk][32 + 4 * tx];
#pragma unroll
            for (int j = 0; j < 4; ++j) {
                float a = (kk == 0) ? av[j].x : (kk == 1) ? av[j].y : (kk == 2) ? av[j].z : av[j].w;
                aclo[j].x += a * blo.x; aclo[j].y += a * blo.y;
                aclo[j].z += a * blo.z; aclo[j].w += a * blo.w;
                achi[j].x += a * bhi.x; achi[j].y += a * bhi.y;
                achi[j].z += a * bhi.z; achi[j].w += a * bhi.w;
            }
        }
    }
#pragma unroll
    for (int j = 0; j < 4; ++j) {
        int row = row0 + ty + 32 * j;
        if (row < N) {
            union { __half2 h[2]; uint2 u; } lo, hi;
            lo.h[0] = __floats2half2_rn(aclo[j].x, aclo[j].y);
            lo.h[1] = __floats2half2_rn(aclo[j].z, aclo[j].w);
            hi.h[0] = __floats2half2_rn(achi[j].x, achi[j].y);
            hi.h[1] = __floats2half2_rn(achi[j].z, achi[j].w);
            uint2* p = (uint2*)(xw2h + (size_t)row * OUT_DIM);
            p[tx] = lo.u;
            p[8 + tx] = hi.u;
        }
    }
}

// ---------------- CSR aggregation (fp16 gather): one wave per dst node ----------------
// agg[d] = dinv[d] * sum_{s in nbr(d)} dinv[s]*xw[s]  +  dinv[d]^2 * xw[d]
template <int F>  // 128 or 64
__global__ __launch_bounds__(256) void k_agg(const int* __restrict__ row_ptr,
                                             const int* __restrict__ csr_src,
                                             const float* __restrict__ dinv,
                                             const __half* __restrict__ xwh,
                                             float* __restrict__ agg, int N) {
    constexpr int L = F / 8;       // lanes per row: 16 (F=128) or 8 (F=64), 16B/lane
    constexpr int EPW = 64 / L;    // edges in flight per wave: 4 or 8
    int node = (blockIdx.x * 256 + threadIdx.x) >> 6;  // one wave per node
    if (node >= N) return;
    int lane = threadIdx.x & 63;
    int sub = lane / L;
    int c   = lane % L;            // 8-half chunk index
    int beg = row_ptr[node], end = row_ptr[node + 1];
    float a0 = 0.f, a1 = 0.f, a2 = 0.f, a3 = 0.f;
    float a4 = 0.f, a5 = 0.f, a6 = 0.f, a7 = 0.f;
    for (int j = beg + sub; j < end; j += EPW) {
        int s = csr_src[j];
        float nrm = dinv[s];
        uint4 u = *(const uint4*)(xwh + (size_t)s * F + c * 8);
        float2 v0 = __half22float2(*(__half2*)&u.x);
        float2 v1 = __half22float2(*(__half2*)&u.y);
        float2 v2 = __half22float2(*(__half2*)&u.z);
        float2 v3 = __half22float2(*(__half2*)&u.w);
        a0 += v0.x * nrm; a1 += v0.y * nrm;
        a2 += v1.x * nrm; a3 += v1.y * nrm;
        a4 += v2.x * nrm; a5 += v2.y * nrm;
        a6 += v3.x * nrm; a7 += v3.y * nrm;
    }
#pragma unroll
    for (int off = L; off < 64; off <<= 1) {
        a0 += __shfl_xor(a0, off); a1 += __shfl_xor(a1, off);
        a2 += __shfl_xor(a2, off); a3 += __shfl_xor(a3, off);
        a4 += __shfl_xor(a4, off); a5 += __shfl_xor(a5, off);
        a6 += __shfl_xor(a6, off); a7 += __shfl_xor(a7, off);
    }
    float dd = dinv[node];
    float s2 = dd * dd;
    uint4 u = *(const uint4*)(xwh + (size_t)node * F + c * 8);
    float2 v0 = __half22float2(*(__half2*)&u.x);
    float2 v1 = __half22float2(*(__half2*)&u.y);
    float2 v2 = __half22float2(*(__half2*)&u.z);
    float2 v3 = __half22float2(*(__half2*)&u.w);
    if (sub == 0) {
        float4 r0, r1;
        r0.x = a0 * dd + v0.x * s2; r0.y = a1 * dd + v0.y * s2;
        r0.z = a2 * dd + v1.x * s2; r0.w = a3 * dd + v1.y * s2;
        r1.x = a4 * dd + v2.x * s2; r1.y = a5 * dd + v2.y * s2;
        r1.z = a6 * dd + v3.x * s2; r1.w = a7 * dd + v3.y * s2;
        float* o = agg + (size_t)node * F + c * 8;
        *(float4*)o = r0;
        *(float4*)(o + 4) = r1;
    }
}

// ---------------- final: out = leaky_relu((agg2 + b2) @ Wfc + bfc) ----------------
__global__ __launch_bounds__(256) void k_final(const float* __restrict__ agg2,
                                               const float* __restrict__ b2,
                                               const float* __restrict__ Wfc,
                                               const float* __restrict__ bfc,
                                               float* __restrict__ out, int N) {
    __shared__ float tile[128][68];
    __shared__ float wf[OUT_DIM * 2];
    __shared__ float bf[2];
    int tid = threadIdx.x;
    if (tid < 32) ((float4*)wf)[tid] = ((const float4*)Wfc)[tid];
    if (tid == 32) { bf[0] = bfc[0]; bf[1] = bfc[1]; }
    int row0 = blockIdx.x * 128;
#pragma unroll
    for (int i = 0; i < 8; ++i) {
        int q = tid + 256 * i;          // 2048 float4
        int r = q >> 4, c4 = q & 15;
        int row = row0 + r;
        if (row < N) {
            float4 v = *(const float4*)(agg2 + (size_t)row * OUT_DIM + c4 * 4);
            float4 bb = ((const float4*)b2)[c4];
            v.x += bb.x; v.y += bb.y; v.z += bb.z; v.w += bb.w;
            *(float4*)&tile[r][c4 * 4] = v;
        }
    }
    __syncthreads();
    int i = tid & 127, j = tid >> 7;
    int row = row0 + i;
    if (row < N) {
        float acc = 0.f;
#pragma unroll 8
        for (int k = 0; k < OUT_DIM; ++k) acc += tile[i][k] * wf[k * 2 + j];
        acc += bf[j];
        out[(size_t)row * 2 + j] = acc > 0.f ? acc : 0.01f * acc;
    }
}

extern "C" void kernel_launch(void* const* d_in, const int* in_sizes, int n_in,
                              void* d_out, int out_size, void* d_ws, size_t ws_size,
                              hipStream_t stream) {
    const float* x   = (const float*)d_in[0];
    const int*   ei  = (const int*)d_in[1];
    const float* W1  = (const float*)d_in[2];
    const float* b1  = (const float*)d_in[3];
    const float* W2  = (const float*)d_in[4];
    const float* b2  = (const float*)d_in[5];
    const float* Wfc = (const float*)d_in[6];
    const float* bfc = (const float*)d_in[7];

    const int N = in_sizes[0] / IN_DIM;   // 50000
    const int E = in_sizes[1] / 2;        // 800000
    const int* src = ei;
    const int* dst = ei + E;
    const int nbin = (N + BINW - 1) / BINW;  // 391

    // Workspace layout (256B-aligned regions):
    // row_ptr[N+1] csr_src[E] hist[nbin*256] total[nbin] bin_base[nbin+1] (int)
    // dinv[N] agg1[N*128] (f32) | xw1h[N*128] (f16)
    // ebin aliases agg1's first E*4 bytes (dead before k_agg writes agg1).
    char* base = (char*)d_ws;
    size_t off = 0;
    auto take = [&](size_t bytes) { size_t o = off; off = (off + bytes + 255) & ~(size_t)255; return (void*)(base + o); };
    int*    row_ptr  = (int*)take((size_t)(N + 1) * 4);
    int*    csr_src  = (int*)take((size_t)E * 4);
    int*    hist     = (int*)take((size_t)nbin * EBLK * 4);
    int*    total    = (int*)take((size_t)nbin * 4);
    int*    bin_base = (int*)take((size_t)(nbin + 1) * 4);
    float*  dinv     = (float*)take((size_t)N * 4);
    float*  agg1     = (float*)take((size_t)N * HID_DIM * 4);
    __half* xw1h     = (__half*)take((size_t)N * HID_DIM * 2);
    unsigned int* ebin = (unsigned int*)agg1;
    __half* xw2h = xw1h;
    float*  agg2 = agg1;

    // CSR build (no memsets needed — every array fully written before read)
    k_bin_hist<<<EBLK, 256, 0, stream>>>(dst, hist, E, nbin);
    k_bin_scan<<<nbin, 256, 0, stream>>>(hist, total);
    k_bin_base<<<1, 256, 0, stream>>>(total, bin_base, nbin);
    k_bin_scatter<<<EBLK, 256, 0, stream>>>(src, dst, hist, bin_base, ebin, E, nbin);
    k_bin_fill<<<nbin, 256, 0, stream>>>(ebin, bin_base, row_ptr, csr_src, dinv, N, nbin);

    const int nTile = (N + 127) / 128;

    // Layer 1
    k_gemm1<<<nTile, 256, 0, stream>>>(x, W1, xw1h, N);
    k_agg<HID_DIM><<<(N + 3) / 4, 256, 0, stream>>>(row_ptr, csr_src, dinv, xw1h, agg1, N);

    // Layer 2 (relu + b1 fused into gemm2 staging)
    k_gemm2<<<nTile, 256, 0, stream>>>(agg1, b1, W2, xw2h, N);
    k_agg<OUT_DIM><<<(N + 3) / 4, 256, 0, stream>>>(row_ptr, csr_src, dinv, xw2h, agg2, N);

    // FC + leaky_relu
    k_final<<<(N + 127) / 128, 256, 0, stream>>>(agg2, b2, Wfc, bfc, (float*)d_out, N);
}

// Round 6
// 223.366 us; speedup vs baseline: 9.7880x; 1.0173x over previous
//
#include <hip/hip_runtime.h>
#include <hip/hip_fp16.h>

// Problem constants (from reference): N=50000, E=800000, dims 128->128->64->2.
#define IN_DIM 128
#define HID_DIM 128
#define OUT_DIM 64
#define BINW 128          // nodes per bin (dst >> 7)
#define BINSHIFT 7
#define MAXBIN 512        // LDS capacity bound; nbin = ceil(N/128) = 391 for N=50000
#define EBLK 256          // blocks in edge passes

// ---------------- P1: per-block bin histogram ----------------
__global__ __launch_bounds__(256) void k_bin_hist(const int* __restrict__ dst,
                                                  int* __restrict__ hist, int E, int nbin) {
    __shared__ int h[MAXBIN];
    int tid = threadIdx.x;
    for (int k = tid; k < nbin; k += 256) h[k] = 0;
    __syncthreads();
    int per = E / gridDim.x;
    int base = blockIdx.x * per;
    int end = (blockIdx.x + 1 == gridDim.x) ? E : base + per;
    for (int i = base + tid; i < end; i += 256)
        atomicAdd(&h[dst[i] >> BINSHIFT], 1);
    __syncthreads();
    for (int k = tid; k < nbin; k += 256) hist[k * EBLK + blockIdx.x] = h[k];
}

// ---------------- P2a: scan each bin's 256 per-block counts ----------------
__global__ __launch_bounds__(256) void k_bin_scan(int* __restrict__ hist,
                                                  int* __restrict__ total) {
    __shared__ int part[256];
    int k = blockIdx.x;
    int t = threadIdx.x;
    int v = hist[k * EBLK + t];
    part[t] = v;
    __syncthreads();
    for (int off = 1; off < 256; off <<= 1) {
        int u = (t >= off) ? part[t - off] : 0;
        __syncthreads();
        part[t] += u;
        __syncthreads();
    }
    hist[k * EBLK + t] = part[t] - v;  // exclusive within bin
    if (t == 255) total[k] = part[255];
}

// ---------------- P2b: exclusive scan of bin totals ----------------
__global__ __launch_bounds__(256) void k_bin_base(const int* __restrict__ total,
                                                  int* __restrict__ bin_base, int nbin) {
    __shared__ int part[256];
    int t = threadIdx.x;
    int carry = 0;
    for (int base = 0; base < nbin; base += 256) {
        int i = base + t;
        int v = (i < nbin) ? total[i] : 0;
        part[t] = v;
        __syncthreads();
        for (int off = 1; off < 256; off <<= 1) {
            int u = (t >= off) ? part[t - off] : 0;
            __syncthreads();
            part[t] += u;
            __syncthreads();
        }
        if (i < nbin) bin_base[i] = carry + part[t] - v;
        carry += part[255];
        __syncthreads();
    }
    if (t == 0) bin_base[nbin] = carry;  // == E
}

// ---------------- P3: scatter packed edges into bin segments ----------------
__global__ __launch_bounds__(256) void k_bin_scatter(const int* __restrict__ src,
                                                     const int* __restrict__ dst,
                                                     const int* __restrict__ hist,
                                                     const int* __restrict__ bin_base,
                                                     unsigned int* __restrict__ ebin,
                                                     int E, int nbin) {
    __shared__ int off[MAXBIN];
    int tid = threadIdx.x;
    for (int k = tid; k < nbin; k += 256)
        off[k] = bin_base[k] + hist[k * EBLK + blockIdx.x];
    __syncthreads();
    int per = E / gridDim.x;
    int base = blockIdx.x * per;
    int end = (blockIdx.x + 1 == gridDim.x) ? E : base + per;
    for (int i = base + tid; i < end; i += 256) {
        unsigned int s = (unsigned int)src[i];
        unsigned int d = (unsigned int)dst[i];
        int pos = atomicAdd(&off[d >> BINSHIFT], 1);
        ebin[pos] = s | (d << 16);
    }
}

// ---------------- P4: per-bin fine fill — row_ptr, dinv, csr_src ----------------
__global__ __launch_bounds__(256) void k_bin_fill(const unsigned int* __restrict__ ebin,
                                                  const int* __restrict__ bin_base,
                                                  int* __restrict__ row_ptr,
                                                  int* __restrict__ csr_src,
                                                  float* __restrict__ dinv, int N, int nbin) {
    __shared__ int cnt[BINW];
    __shared__ int excl[BINW];
    __shared__ int start[BINW];
    int k = blockIdx.x;
    int node0 = k * BINW;
    int nn = min(BINW, N - node0);
    int t = threadIdx.x;
    if (t < BINW) cnt[t] = 0;
    __syncthreads();
    int eb = bin_base[k], ee = bin_base[k + 1];
    for (int i = eb + t; i < ee; i += 256)
        atomicAdd(&cnt[(ebin[i] >> 16) - node0], 1);
    __syncthreads();
    if (t < BINW) excl[t] = (t < nn) ? cnt[t] : 0;
    __syncthreads();
    for (int off = 1; off < BINW; off <<= 1) {
        int u = 0;
        if (t < BINW && t >= off) u = excl[t - off];
        __syncthreads();
        if (t < BINW) excl[t] += u;   // inclusive scan
        __syncthreads();
    }
    if (t < nn) {
        int deg = cnt[t];
        int e0 = eb + excl[t] - deg;  // exclusive
        start[t] = e0;
        row_ptr[node0 + t] = e0;
        dinv[node0 + t] = rsqrtf((float)deg + 1.0f);
        cnt[t] = 0;                   // reuse as fill counter
    }
    if (k == nbin - 1 && t == 0) row_ptr[N] = ee;
    __syncthreads();
    for (int i = eb + t; i < ee; i += 256) {
        unsigned int e = ebin[i];
        int s = (int)(e & 0xffffu);
        int dl = (int)(e >> 16) - node0;
        int slot = start[dl] + atomicAdd(&cnt[dl], 1);
        csr_src[slot] = s;
    }
}

// ---------------- GEMM1: xw1h = fp16(dinv[row] * (x @ W1)) ----------------
// Block tile 128x128, 256 threads, 8 rows x 8 cols per thread.
// A is read directly from global: all 16 tx-lanes of a row-group load the same
// float4 (HW broadcast), so each x element is fetched once per block.
// LDS = W only (64 KB) -> 2 blocks/CU.
__global__ __launch_bounds__(256) void k_gemm1(const float* __restrict__ x,
                                               const float* __restrict__ W,
                                               const float* __restrict__ dinv,
                                               __half* __restrict__ xwh, int N) {
    __shared__ float Ws[128][128];   // [k][col]
    int tid = threadIdx.x;
    const float4* W4 = (const float4*)W;
    float4* Ws4 = (float4*)&Ws[0][0];
#pragma unroll
    for (int i = 0; i < 16; ++i) Ws4[tid + 256 * i] = W4[tid + 256 * i];
    __syncthreads();
    int tx = tid & 15, ty = tid >> 4;
    int row0 = blockIdx.x * 128;
    int rows[8];
    const float* xr[8];
#pragma unroll
    for (int j = 0; j < 8; ++j) {
        int row = row0 + ty + 16 * j;
        rows[j] = row;
        if (row > N - 1) row = N - 1;
        xr[j] = x + (size_t)row * IN_DIM;
    }
    float4 aclo[8], achi[8];
#pragma unroll
    for (int j = 0; j < 8; ++j) {
        aclo[j] = make_float4(0.f, 0.f, 0.f, 0.f);
        achi[j] = make_float4(0.f, 0.f, 0.f, 0.f);
    }
#pragma unroll 2
    for (int k4 = 0; k4 < 32; ++k4) {
        float4 av[8];
#pragma unroll
        for (int j = 0; j < 8; ++j) av[j] = *(const float4*)(xr[j] + k4 * 4);
#pragma unroll
        for (int kk = 0; kk < 4; ++kk) {
            float4 blo = *(const float4*)&Ws[k4 * 4 + kk][4 * tx];
            float4 bhi = *(const float4*)&Ws[k4 * 4 + kk][64 + 4 * tx];
#pragma unroll
            for (int j = 0; j < 8; ++j) {
                float a = (kk == 0) ? av[j].x : (kk == 1) ? av[j].y : (kk == 2) ? av[j].z : av[j].w;
                aclo[j].x += a * blo.x; aclo[j].y += a * blo.y;
                aclo[j].z += a * blo.z; aclo[j].w += a * blo.w;
                achi[j].x += a * bhi.x; achi[j].y += a * bhi.y;
                achi[j].z += a * bhi.z; achi[j].w += a * bhi.w;
            }
        }
    }
#pragma unroll
    for (int j = 0; j < 8; ++j) {
        if (rows[j] < N) {
            float dd = dinv[rows[j]];
            union { __half2 h[2]; uint2 u; } lo, hi;
            lo.h[0] = __floats2half2_rn(aclo[j].x * dd, aclo[j].y * dd);
            lo.h[1] = __floats2half2_rn(aclo[j].z * dd, aclo[j].w * dd);
            hi.h[0] = __floats2half2_rn(achi[j].x * dd, achi[j].y * dd);
            hi.h[1] = __floats2half2_rn(achi[j].z * dd, achi[j].w * dd);
            uint2* p = (uint2*)(xwh + (size_t)rows[j] * HID_DIM);
            p[tx] = lo.u;
            p[16 + tx] = hi.u;
        }
    }
}

// ---------------- GEMM2: xw2h = fp16(dinv[row] * (relu(agg1+b1) @ W2)) ----------------
// Block tile 128x64, 256 threads, 4 rows x 8 cols. A direct from global with
// inline bias+relu (8 tx-lanes broadcast). LDS = W (32 KB) + b1 -> 4 blocks/CU.
__global__ __launch_bounds__(256) void k_gemm2(const float* __restrict__ agg1,
                                               const float* __restrict__ b1,
                                               const float* __restrict__ W2,
                                               const float* __restrict__ dinv,
                                               __half* __restrict__ xw2h, int N) {
    __shared__ float Ws[128][OUT_DIM];
    __shared__ float b1s[HID_DIM];
    int tid = threadIdx.x;
    if (tid < 32) ((float4*)b1s)[tid] = ((const float4*)b1)[tid];
    const float4* W4 = (const float4*)W2;
    float4* Ws4 = (float4*)&Ws[0][0];
#pragma unroll
    for (int i = 0; i < 8; ++i) Ws4[tid + 256 * i] = W4[tid + 256 * i];
    __syncthreads();
    int tx = tid & 7, ty = tid >> 3;
    int row0 = blockIdx.x * 128;
    int rows[4];
    const float* ar[4];
#pragma unroll
    for (int j = 0; j < 4; ++j) {
        int row = row0 + ty + 32 * j;
        rows[j] = row;
        if (row > N - 1) row = N - 1;
        ar[j] = agg1 + (size_t)row * HID_DIM;
    }
    float4 aclo[4], achi[4];
#pragma unroll
    for (int j = 0; j < 4; ++j) {
        aclo[j] = make_float4(0.f, 0.f, 0.f, 0.f);
        achi[j] = make_float4(0.f, 0.f, 0.f, 0.f);
    }
#pragma unroll 2
    for (int k4 = 0; k4 < 32; ++k4) {
        float4 bb = ((const float4*)b1s)[k4];
        float4 av[4];
#pragma unroll
        for (int j = 0; j < 4; ++j) {
            float4 v = *(const float4*)(ar[j] + k4 * 4);
            v.x = fmaxf(v.x + bb.x, 0.f);
            v.y = fmaxf(v.y + bb.y, 0.f);
            v.z = fmaxf(v.z + bb.z, 0.f);
            v.w = fmaxf(v.w + bb.w, 0.f);
            av[j] = v;
        }
#pragma unroll
        for (int kk = 0; kk < 4; ++kk) {
            float4 blo = *(const float4*)&Ws[k4 * 4 + kk][4 * tx];
            float4 bhi = *(const float4*)&Ws[k4 * 4 + kk][32 + 4 * tx];
#pragma unroll
            for (int j = 0; j < 4; ++j) {
                float a = (kk == 0) ? av[j].x : (kk == 1) ? av[j].y : (kk == 2) ? av[j].z : av[j].w;
                aclo[j].x += a * blo.x; aclo[j].y += a * blo.y;
                aclo[j].z += a * blo.z; aclo[j].w += a * blo.w;
                achi[j].x += a * bhi.x; achi[j].y += a * bhi.y;
                achi[j].z += a * bhi.z; achi[j].w += a * bhi.w;
            }
        }
    }
#pragma unroll
    for (int j = 0; j < 4; ++j) {
        if (rows[j] < N) {
            float dd = dinv[rows[j]];
            union { __half2 h[2]; uint2 u; } lo, hi;
            lo.h[0] = __floats2half2_rn(aclo[j].x * dd, aclo[j].y * dd);
            lo.h[1] = __floats2half2_rn(aclo[j].z * dd, aclo[j].w * dd);
            hi.h[0] = __floats2half2_rn(achi[j].x * dd, achi[j].y * dd);
            hi.h[1] = __floats2half2_rn(achi[j].z * dd, achi[j].w * dd);
            uint2* p = (uint2*)(xw2h + (size_t)rows[j] * OUT_DIM);
            p[tx] = lo.u;
            p[8 + tx] = hi.u;
        }
    }
}

// ---------------- Layer-1 aggregation: agg1[d] = dinv[d]*(sum xwh[s] + xwh[d]) ----------------
// xwh is pre-scaled by dinv at GEMM output. One wave per node, 16 lanes/row.
__global__ __launch_bounds__(256) void k_agg1(const int* __restrict__ row_ptr,
                                              const int* __restrict__ csr_src,
                                              const float* __restrict__ dinv,
                                              const __half* __restrict__ xwh,
                                              float* __restrict__ agg, int N) {
    constexpr int F = HID_DIM;
    constexpr int L = F / 8;       // 16 lanes per row, 16B/lane
    constexpr int EPW = 64 / L;    // 4 edges in flight
    int node = (blockIdx.x * 256 + threadIdx.x) >> 6;
    if (node >= N) return;
    int lane = threadIdx.x & 63;
    int sub = lane / L;
    int c   = lane % L;
    int beg = row_ptr[node], end = row_ptr[node + 1];
    float a0 = 0.f, a1 = 0.f, a2 = 0.f, a3 = 0.f;
    float a4 = 0.f, a5 = 0.f, a6 = 0.f, a7 = 0.f;
    for (int j = beg + sub; j < end; j += EPW) {
        int s = csr_src[j];
        uint4 u = *(const uint4*)(xwh + (size_t)s * F + c * 8);
        float2 v0 = __half22float2(*(__half2*)&u.x);
        float2 v1 = __half22float2(*(__half2*)&u.y);
        float2 v2 = __half22float2(*(__half2*)&u.z);
        float2 v3 = __half22float2(*(__half2*)&u.w);
        a0 += v0.x; a1 += v0.y; a2 += v1.x; a3 += v1.y;
        a4 += v2.x; a5 += v2.y; a6 += v3.x; a7 += v3.y;
    }
#pragma unroll
    for (int off = L; off < 64; off <<= 1) {
        a0 += __shfl_xor(a0, off); a1 += __shfl_xor(a1, off);
        a2 += __shfl_xor(a2, off); a3 += __shfl_xor(a3, off);
        a4 += __shfl_xor(a4, off); a5 += __shfl_xor(a5, off);
        a6 += __shfl_xor(a6, off); a7 += __shfl_xor(a7, off);
    }
    if (sub == 0) {
        uint4 u = *(const uint4*)(xwh + (size_t)node * F + c * 8);
        float2 v0 = __half22float2(*(__half2*)&u.x);
        float2 v1 = __half22float2(*(__half2*)&u.y);
        float2 v2 = __half22float2(*(__half2*)&u.z);
        float2 v3 = __half22float2(*(__half2*)&u.w);
        float dd = dinv[node];
        float4 r0, r1;
        r0.x = (a0 + v0.x) * dd; r0.y = (a1 + v0.y) * dd;
        r0.z = (a2 + v1.x) * dd; r0.w = (a3 + v1.y) * dd;
        r1.x = (a4 + v2.x) * dd; r1.y = (a5 + v2.y) * dd;
        r1.z = (a6 + v3.x) * dd; r1.w = (a7 + v3.y) * dd;
        float* o = agg + (size_t)node * F + c * 8;
        *(float4*)o = r0;
        *(float4*)(o + 4) = r1;
    }
}

// ---------------- Layer-2 aggregation FUSED with FC + leaky_relu ----------------
// agg2[d] = dinv[d]*(sum xw2h[s] + xw2h[d]); out[d] = leaky((agg2+b2)@Wfc + bfc)
__global__ __launch_bounds__(256) void k_agg_final(const int* __restrict__ row_ptr,
                                                   const int* __restrict__ csr_src,
                                                   const float* __restrict__ dinv,
                                                   const __half* __restrict__ xwh,
                                                   const float* __restrict__ b2,
                                                   const float* __restrict__ Wfc,
                                                   const float* __restrict__ bfc,
                                                   float* __restrict__ out, int N) {
    constexpr int F = OUT_DIM;
    constexpr int L = F / 8;       // 8 lanes per row
    constexpr int EPW = 64 / L;    // 8 edges in flight
    __shared__ float wfs[OUT_DIM * 2];
    __shared__ float b2s[OUT_DIM];
    __shared__ float bfs[2];
    int tid = threadIdx.x;
    if (tid < 32) ((float4*)wfs)[tid] = ((const float4*)Wfc)[tid];
    else if (tid < 48) ((float4*)b2s)[tid - 32] = ((const float4*)b2)[tid - 32];
    else if (tid == 48) { bfs[0] = bfc[0]; bfs[1] = bfc[1]; }
    __syncthreads();
    int node = (blockIdx.x * 256 + tid) >> 6;
    if (node >= N) return;
    int lane = tid & 63;
    int sub = lane / L;
    int c   = lane % L;
    int beg = row_ptr[node], end = row_ptr[node + 1];
    float a0 = 0.f, a1 = 0.f, a2 = 0.f, a3 = 0.f;
    float a4 = 0.f, a5 = 0.f, a6 = 0.f, a7 = 0.f;
    for (int j = beg + sub; j < end; j += EPW) {
        int s = csr_src[j];
        uint4 u = *(const uint4*)(xwh + (size_t)s * F + c * 8);
        float2 v0 = __half22float2(*(__half2*)&u.x);
        float2 v1 = __half22float2(*(__half2*)&u.y);
        float2 v2 = __half22float2(*(__half2*)&u.z);
        float2 v3 = __half22float2(*(__half2*)&u.w);
        a0 += v0.x; a1 += v0.y; a2 += v1.x; a3 += v1.y;
        a4 += v2.x; a5 += v2.y; a6 += v3.x; a7 += v3.y;
    }
#pragma unroll
    for (int off = L; off < 64; off <<= 1) {
        a0 += __shfl_xor(a0, off); a1 += __shfl_xor(a1, off);
        a2 += __shfl_xor(a2, off); a3 += __shfl_xor(a3, off);
        a4 += __shfl_xor(a4, off); a5 += __shfl_xor(a5, off);
        a6 += __shfl_xor(a6, off); a7 += __shfl_xor(a7, off);
    }
    // self + FC partial dot (all lanes hold the full column sums for their c)
    uint4 u = *(const uint4*)(xwh + (size_t)node * F + c * 8);
    float2 v0 = __half22float2(*(__half2*)&u.x);
    float2 v1 = __half22float2(*(__half2*)&u.y);
    float2 v2 = __half22float2(*(__half2*)&u.z);
    float2 v3 = __half22float2(*(__half2*)&u.w);
    float dd = dinv[node];
    float h[8];
    h[0] = (a0 + v0.x) * dd; h[1] = (a1 + v0.y) * dd;
    h[2] = (a2 + v1.x) * dd; h[3] = (a3 + v1.y) * dd;
    h[4] = (a4 + v2.x) * dd; h[5] = (a5 + v2.y) * dd;
    h[6] = (a6 + v3.x) * dd; h[7] = (a7 + v3.y) * dd;
    float o0 = 0.f, o1 = 0.f;
#pragma unroll
    for (int k = 0; k < 8; ++k) {
        float hv = h[k] + b2s[c * 8 + k];
        o0 += hv * wfs[(c * 8 + k) * 2 + 0];
        o1 += hv * wfs[(c * 8 + k) * 2 + 1];
    }
#pragma unroll
    for (int off = 1; off < L; off <<= 1) {
        o0 += __shfl_xor(o0, off);
        o1 += __shfl_xor(o1, off);
    }
    if (lane == 0) {
        o0 += bfs[0]; o1 += bfs[1];
        float2 r;
        r.x = o0 > 0.f ? o0 : 0.01f * o0;
        r.y = o1 > 0.f ? o1 : 0.01f * o1;
        *(float2*)(out + (size_t)node * 2) = r;
    }
}

extern "C" void kernel_launch(void* const* d_in, const int* in_sizes, int n_in,
                              void* d_out, int out_size, void* d_ws, size_t ws_size,
                              hipStream_t stream) {
    const float* x   = (const float*)d_in[0];
    const int*   ei  = (const int*)d_in[1];
    const float* W1  = (const float*)d_in[2];
    const float* b1  = (const float*)d_in[3];
    const float* W2  = (const float*)d_in[4];
    const float* b2  = (const float*)d_in[5];
    const float* Wfc = (const float*)d_in[6];
    const float* bfc = (const float*)d_in[7];

    const int N = in_sizes[0] / IN_DIM;   // 50000
    const int E = in_sizes[1] / 2;        // 800000
    const int* src = ei;
    const int* dst = ei + E;
    const int nbin = (N + BINW - 1) / BINW;  // 391

    // Workspace layout (256B-aligned regions):
    // row_ptr[N+1] csr_src[E] hist[nbin*256] total[nbin] bin_base[nbin+1] (int)
    // dinv[N] agg1[N*128] (f32) | xw1h[N*128] (f16)
    // ebin aliases agg1's first E*4 bytes (dead before k_agg1 writes agg1).
    char* base = (char*)d_ws;
    size_t off = 0;
    auto take = [&](size_t bytes) { size_t o = off; off = (off + bytes + 255) & ~(size_t)255; return (void*)(base + o); };
    int*    row_ptr  = (int*)take((size_t)(N + 1) * 4);
    int*    csr_src  = (int*)take((size_t)E * 4);
    int*    hist     = (int*)take((size_t)nbin * EBLK * 4);
    int*    total    = (int*)take((size_t)nbin * 4);
    int*    bin_base = (int*)take((size_t)(nbin + 1) * 4);
    float*  dinv     = (float*)take((size_t)N * 4);
    float*  agg1     = (float*)take((size_t)N * HID_DIM * 4);
    __half* xw1h     = (__half*)take((size_t)N * HID_DIM * 2);
    unsigned int* ebin = (unsigned int*)agg1;
    __half* xw2h = xw1h;

    // CSR build (no memsets needed — every array fully written before read)
    k_bin_hist<<<EBLK, 256, 0, stream>>>(dst, hist, E, nbin);
    k_bin_scan<<<nbin, 256, 0, stream>>>(hist, total);
    k_bin_base<<<1, 256, 0, stream>>>(total, bin_base, nbin);
    k_bin_scatter<<<EBLK, 256, 0, stream>>>(src, dst, hist, bin_base, ebin, E, nbin);
    k_bin_fill<<<nbin, 256, 0, stream>>>(ebin, bin_base, row_ptr, csr_src, dinv, N, nbin);

    const int nTile = (N + 127) / 128;

    // Layer 1
    k_gemm1<<<nTile, 256, 0, stream>>>(x, W1, dinv, xw1h, N);
    k_agg1<<<(N + 3) / 4, 256, 0, stream>>>(row_ptr, csr_src, dinv, xw1h, agg1, N);

    // Layer 2 (relu + b1 fused into gemm2 A-load; FC + leaky fused into agg)
    k_gemm2<<<nTile, 256, 0, stream>>>(agg1, b1, W2, dinv, xw2h, N);
    k_agg_final<<<(N + 3) / 4, 256, 0, stream>>>(row_ptr, csr_src, dinv, xw2h,
                                                 b2, Wfc, bfc, (float*)d_out, N);
}

// Round 7
// 212.097 us; speedup vs baseline: 10.3081x; 1.0531x over previous
//
#include <hip/hip_runtime.h>
#include <hip/hip_fp16.h>

// Problem constants (from reference): N=50000, E=800000, dims 128->128->64->2.
#define IN_DIM 128
#define HID_DIM 128
#define OUT_DIM 64
#define BINW 128          // nodes per bin (dst >> 7)
#define BINSHIFT 7
#define MAXBIN 512        // LDS capacity bound; nbin = ceil(N/128) = 391 for N=50000
#define EBLK 256          // blocks in edge passes

// ---------------- P1: per-block bin histogram ----------------
__global__ __launch_bounds__(256) void k_bin_hist(const int* __restrict__ dst,
                                                  int* __restrict__ hist, int E, int nbin) {
    __shared__ int h[MAXBIN];
    int tid = threadIdx.x;
    for (int k = tid; k < nbin; k += 256) h[k] = 0;
    __syncthreads();
    int per = E / gridDim.x;
    int base = blockIdx.x * per;
    int end = (blockIdx.x + 1 == gridDim.x) ? E : base + per;
    for (int i = base + tid; i < end; i += 256)
        atomicAdd(&h[dst[i] >> BINSHIFT], 1);
    __syncthreads();
    for (int k = tid; k < nbin; k += 256) hist[k * EBLK + blockIdx.x] = h[k];
}

// ---------------- P2a: scan each bin's 256 per-block counts ----------------
__global__ __launch_bounds__(256) void k_bin_scan(int* __restrict__ hist,
                                                  int* __restrict__ total) {
    __shared__ int part[256];
    int k = blockIdx.x;
    int t = threadIdx.x;
    int v = hist[k * EBLK + t];
    part[t] = v;
    __syncthreads();
    for (int off = 1; off < 256; off <<= 1) {
        int u = (t >= off) ? part[t - off] : 0;
        __syncthreads();
        part[t] += u;
        __syncthreads();
    }
    hist[k * EBLK + t] = part[t] - v;  // exclusive within bin
    if (t == 255) total[k] = part[255];
}

// ---------------- P2b: exclusive scan of bin totals ----------------
__global__ __launch_bounds__(256) void k_bin_base(const int* __restrict__ total,
                                                  int* __restrict__ bin_base, int nbin) {
    __shared__ int part[256];
    int t = threadIdx.x;
    int carry = 0;
    for (int base = 0; base < nbin; base += 256) {
        int i = base + t;
        int v = (i < nbin) ? total[i] : 0;
        part[t] = v;
        __syncthreads();
        for (int off = 1; off < 256; off <<= 1) {
            int u = (t >= off) ? part[t - off] : 0;
            __syncthreads();
            part[t] += u;
            __syncthreads();
        }
        if (i < nbin) bin_base[i] = carry + part[t] - v;
        carry += part[255];
        __syncthreads();
    }
    if (t == 0) bin_base[nbin] = carry;  // == E
}

// ---------------- P3: scatter packed edges into bin segments ----------------
__global__ __launch_bounds__(256) void k_bin_scatter(const int* __restrict__ src,
                                                     const int* __restrict__ dst,
                                                     const int* __restrict__ hist,
                                                     const int* __restrict__ bin_base,
                                                     unsigned int* __restrict__ ebin,
                                                     int E, int nbin) {
    __shared__ int off[MAXBIN];
    int tid = threadIdx.x;
    for (int k = tid; k < nbin; k += 256)
        off[k] = bin_base[k] + hist[k * EBLK + blockIdx.x];
    __syncthreads();
    int per = E / gridDim.x;
    int base = blockIdx.x * per;
    int end = (blockIdx.x + 1 == gridDim.x) ? E : base + per;
    for (int i = base + tid; i < end; i += 256) {
        unsigned int s = (unsigned int)src[i];
        unsigned int d = (unsigned int)dst[i];
        int pos = atomicAdd(&off[d >> BINSHIFT], 1);
        ebin[pos] = s | (d << 16);
    }
}

// ---------------- P4: per-bin fine fill — row_ptr, dinv, csr_src ----------------
__global__ __launch_bounds__(256) void k_bin_fill(const unsigned int* __restrict__ ebin,
                                                  const int* __restrict__ bin_base,
                                                  int* __restrict__ row_ptr,
                                                  int* __restrict__ csr_src,
                                                  float* __restrict__ dinv, int N, int nbin) {
    __shared__ int cnt[BINW];
    __shared__ int excl[BINW];
    __shared__ int start[BINW];
    int k = blockIdx.x;
    int node0 = k * BINW;
    int nn = min(BINW, N - node0);
    int t = threadIdx.x;
    if (t < BINW) cnt[t] = 0;
    __syncthreads();
    int eb = bin_base[k], ee = bin_base[k + 1];
    for (int i = eb + t; i < ee; i += 256)
        atomicAdd(&cnt[(ebin[i] >> 16) - node0], 1);
    __syncthreads();
    if (t < BINW) excl[t] = (t < nn) ? cnt[t] : 0;
    __syncthreads();
    for (int off = 1; off < BINW; off <<= 1) {
        int u = 0;
        if (t < BINW && t >= off) u = excl[t - off];
        __syncthreads();
        if (t < BINW) excl[t] += u;   // inclusive scan
        __syncthreads();
    }
    if (t < nn) {
        int deg = cnt[t];
        int e0 = eb + excl[t] - deg;  // exclusive
        start[t] = e0;
        row_ptr[node0 + t] = e0;
        dinv[node0 + t] = rsqrtf((float)deg + 1.0f);
        cnt[t] = 0;                   // reuse as fill counter
    }
    if (k == nbin - 1 && t == 0) row_ptr[N] = ee;
    __syncthreads();
    for (int i = eb + t; i < ee; i += 256) {
        unsigned int e = ebin[i];
        int s = (int)(e & 0xffffu);
        int dl = (int)(e >> 16) - node0;
        int slot = start[dl] + atomicAdd(&cnt[dl], 1);
        csr_src[slot] = s;
    }
}

// ---------------- GEMM1: xw1h = fp16(dinv[row] * (x @ W1)) ----------------
// Block tile 128x128, 256 threads, 8 rows x 8 cols per thread. A from global
// (16-lane broadcast). LDS = W only (64 KB) -> 2 blocks/CU.
__global__ __launch_bounds__(256) void k_gemm1(const float* __restrict__ x,
                                               const float* __restrict__ W,
                                               const float* __restrict__ dinv,
                                               __half* __restrict__ xwh, int N) {
    __shared__ float Ws[128][128];   // [k][col]
    int tid = threadIdx.x;
    const float4* W4 = (const float4*)W;
    float4* Ws4 = (float4*)&Ws[0][0];
#pragma unroll
    for (int i = 0; i < 16; ++i) Ws4[tid + 256 * i] = W4[tid + 256 * i];
    __syncthreads();
    int tx = tid & 15, ty = tid >> 4;
    int row0 = blockIdx.x * 128;
    int rows[8];
    const float* xr[8];
#pragma unroll
    for (int j = 0; j < 8; ++j) {
        int row = row0 + ty + 16 * j;
        rows[j] = row;
        if (row > N - 1) row = N - 1;
        xr[j] = x + (size_t)row * IN_DIM;
    }
    float4 aclo[8], achi[8];
#pragma unroll
    for (int j = 0; j < 8; ++j) {
        aclo[j] = make_float4(0.f, 0.f, 0.f, 0.f);
        achi[j] = make_float4(0.f, 0.f, 0.f, 0.f);
    }
#pragma unroll 2
    for (int k4 = 0; k4 < 32; ++k4) {
        float4 av[8];
#pragma unroll
        for (int j = 0; j < 8; ++j) av[j] = *(const float4*)(xr[j] + k4 * 4);
#pragma unroll
        for (int kk = 0; kk < 4; ++kk) {
            float4 blo = *(const float4*)&Ws[k4 * 4 + kk][4 * tx];
            float4 bhi = *(const float4*)&Ws[k4 * 4 + kk][64 + 4 * tx];
#pragma unroll
            for (int j = 0; j < 8; ++j) {
                float a = (kk == 0) ? av[j].x : (kk == 1) ? av[j].y : (kk == 2) ? av[j].z : av[j].w;
                aclo[j].x += a * blo.x; aclo[j].y += a * blo.y;
                aclo[j].z += a * blo.z; aclo[j].w += a * blo.w;
                achi[j].x += a * bhi.x; achi[j].y += a * bhi.y;
                achi[j].z += a * bhi.z; achi[j].w += a * bhi.w;
            }
        }
    }
#pragma unroll
    for (int j = 0; j < 8; ++j) {
        if (rows[j] < N) {
            float dd = dinv[rows[j]];
            union { __half2 h[2]; uint2 u; } lo, hi;
            lo.h[0] = __floats2half2_rn(aclo[j].x * dd, aclo[j].y * dd);
            lo.h[1] = __floats2half2_rn(aclo[j].z * dd, aclo[j].w * dd);
            hi.h[0] = __floats2half2_rn(achi[j].x * dd, achi[j].y * dd);
            hi.h[1] = __floats2half2_rn(achi[j].z * dd, achi[j].w * dd);
            uint2* p = (uint2*)(xwh + (size_t)rows[j] * HID_DIM);
            p[tx] = lo.u;
            p[16 + tx] = hi.u;
        }
    }
}

// ---------------- Layer-1 aggregation + bias + ReLU, fp16 out ----------------
// xr1h[d] = fp16(relu(dinv[d]*(sum_s xwh[s] + xwh[d]) + b1))   (xwh pre-scaled by dinv)
// One wave per node, 16 lanes/row, 2x-unrolled gather (8 rows in flight/wave).
__global__ __launch_bounds__(256) void k_agg1(const int* __restrict__ row_ptr,
                                              const int* __restrict__ csr_src,
                                              const float* __restrict__ dinv,
                                              const __half* __restrict__ xwh,
                                              const float* __restrict__ b1,
                                              __half* __restrict__ xr1h, int N) {
    constexpr int F = HID_DIM;
    constexpr int L = F / 8;       // 16 lanes per row, 16B/lane
    constexpr int EPW = 64 / L;    // 4 edge slots per wave
    int node = (blockIdx.x * 256 + threadIdx.x) >> 6;
    if (node >= N) return;
    int lane = threadIdx.x & 63;
    int sub = lane / L;
    int c   = lane % L;
    int beg = row_ptr[node], end = row_ptr[node + 1];
    // hoisted loads (overlap with gather)
    float dd = dinv[node];
    uint4 us = *(const uint4*)(xwh + (size_t)node * F + c * 8);
    float4 b1a = *(const float4*)(b1 + c * 8);
    float4 b1b = *(const float4*)(b1 + c * 8 + 4);
    float a0 = 0.f, a1 = 0.f, a2 = 0.f, a3 = 0.f;
    float a4 = 0.f, a5 = 0.f, a6 = 0.f, a7 = 0.f;
    int j = beg + sub;
    for (; j + EPW < end; j += 2 * EPW) {
        int s0 = csr_src[j];
        int s1 = csr_src[j + EPW];
        uint4 u0 = *(const uint4*)(xwh + (size_t)s0 * F + c * 8);
        uint4 u1 = *(const uint4*)(xwh + (size_t)s1 * F + c * 8);
        float2 v0 = __half22float2(*(__half2*)&u0.x);
        float2 v1 = __half22float2(*(__half2*)&u0.y);
        float2 v2 = __half22float2(*(__half2*)&u0.z);
        float2 v3 = __half22float2(*(__half2*)&u0.w);
        a0 += v0.x; a1 += v0.y; a2 += v1.x; a3 += v1.y;
        a4 += v2.x; a5 += v2.y; a6 += v3.x; a7 += v3.y;
        v0 = __half22float2(*(__half2*)&u1.x);
        v1 = __half22float2(*(__half2*)&u1.y);
        v2 = __half22float2(*(__half2*)&u1.z);
        v3 = __half22float2(*(__half2*)&u1.w);
        a0 += v0.x; a1 += v0.y; a2 += v1.x; a3 += v1.y;
        a4 += v2.x; a5 += v2.y; a6 += v3.x; a7 += v3.y;
    }
    if (j < end) {
        int s = csr_src[j];
        uint4 u = *(const uint4*)(xwh + (size_t)s * F + c * 8);
        float2 v0 = __half22float2(*(__half2*)&u.x);
        float2 v1 = __half22float2(*(__half2*)&u.y);
        float2 v2 = __half22float2(*(__half2*)&u.z);
        float2 v3 = __half22float2(*(__half2*)&u.w);
        a0 += v0.x; a1 += v0.y; a2 += v1.x; a3 += v1.y;
        a4 += v2.x; a5 += v2.y; a6 += v3.x; a7 += v3.y;
    }
#pragma unroll
    for (int off = L; off < 64; off <<= 1) {
        a0 += __shfl_xor(a0, off); a1 += __shfl_xor(a1, off);
        a2 += __shfl_xor(a2, off); a3 += __shfl_xor(a3, off);
        a4 += __shfl_xor(a4, off); a5 += __shfl_xor(a5, off);
        a6 += __shfl_xor(a6, off); a7 += __shfl_xor(a7, off);
    }
    if (sub == 0) {
        float2 v0 = __half22float2(*(__half2*)&us.x);
        float2 v1 = __half22float2(*(__half2*)&us.y);
        float2 v2 = __half22float2(*(__half2*)&us.z);
        float2 v3 = __half22float2(*(__half2*)&us.w);
        float h0 = fmaxf((a0 + v0.x) * dd + b1a.x, 0.f);
        float h1 = fmaxf((a1 + v0.y) * dd + b1a.y, 0.f);
        float h2 = fmaxf((a2 + v1.x) * dd + b1a.z, 0.f);
        float h3 = fmaxf((a3 + v1.y) * dd + b1a.w, 0.f);
        float h4 = fmaxf((a4 + v2.x) * dd + b1b.x, 0.f);
        float h5 = fmaxf((a5 + v2.y) * dd + b1b.y, 0.f);
        float h6 = fmaxf((a6 + v3.x) * dd + b1b.z, 0.f);
        float h7 = fmaxf((a7 + v3.y) * dd + b1b.w, 0.f);
        union { __half2 h[4]; uint4 u; } o;
        o.h[0] = __floats2half2_rn(h0, h1);
        o.h[1] = __floats2half2_rn(h2, h3);
        o.h[2] = __floats2half2_rn(h4, h5);
        o.h[3] = __floats2half2_rn(h6, h7);
        *(uint4*)(xr1h + (size_t)node * F + c * 8) = o.u;
    }
}

// ---------------- GEMM2: xw2h = fp16(dinv[row] * (xr1h @ W2)) ----------------
// A is fp16 (already relu+bias). Block tile 128x64, 4 rows x 8 cols per thread.
// LDS = W2 only (32 KB).
__global__ __launch_bounds__(256) void k_gemm2(const __half* __restrict__ xr1h,
                                               const float* __restrict__ W2,
                                               const float* __restrict__ dinv,
                                               __half* __restrict__ xw2h, int N) {
    __shared__ float Ws[128][OUT_DIM];
    int tid = threadIdx.x;
    const float4* W4 = (const float4*)W2;
    float4* Ws4 = (float4*)&Ws[0][0];
#pragma unroll
    for (int i = 0; i < 8; ++i) Ws4[tid + 256 * i] = W4[tid + 256 * i];
    __syncthreads();
    int tx = tid & 7, ty = tid >> 3;
    int row0 = blockIdx.x * 128;
    int rows[4];
    const __half* ar[4];
#pragma unroll
    for (int j = 0; j < 4; ++j) {
        int row = row0 + ty + 32 * j;
        rows[j] = row;
        if (row > N - 1) row = N - 1;
        ar[j] = xr1h + (size_t)row * HID_DIM;
    }
    float4 aclo[4], achi[4];
#pragma unroll
    for (int j = 0; j < 4; ++j) {
        aclo[j] = make_float4(0.f, 0.f, 0.f, 0.f);
        achi[j] = make_float4(0.f, 0.f, 0.f, 0.f);
    }
#pragma unroll 2
    for (int k8 = 0; k8 < 16; ++k8) {
        float a8[4][8];
#pragma unroll
        for (int j = 0; j < 4; ++j) {
            uint4 u = *(const uint4*)(ar[j] + k8 * 8);
            float2 v0 = __half22float2(*(__half2*)&u.x);
            float2 v1 = __half22float2(*(__half2*)&u.y);
            float2 v2 = __half22float2(*(__half2*)&u.z);
            float2 v3 = __half22float2(*(__half2*)&u.w);
            a8[j][0] = v0.x; a8[j][1] = v0.y; a8[j][2] = v1.x; a8[j][3] = v1.y;
            a8[j][4] = v2.x; a8[j][5] = v2.y; a8[j][6] = v3.x; a8[j][7] = v3.y;
        }
#pragma unroll
        for (int kk = 0; kk < 8; ++kk) {
            float4 blo = *(const float4*)&Ws[k8 * 8 + kk][4 * tx];
            float4 bhi = *(const float4*)&Ws[k8 * 8 + kk][32 + 4 * tx];
#pragma unroll
            for (int j = 0; j < 4; ++j) {
                float a = a8[j][kk];
                aclo[j].x += a * blo.x; aclo[j].y += a * blo.y;
                aclo[j].z += a * blo.z; aclo[j].w += a * blo.w;
                achi[j].x += a * bhi.x; achi[j].y += a * bhi.y;
                achi[j].z += a * bhi.z; achi[j].w += a * bhi.w;
            }
        }
    }
#pragma unroll
    for (int j = 0; j < 4; ++j) {
        if (rows[j] < N) {
            float dd = dinv[rows[j]];
            union { __half2 h[2]; uint2 u; } lo, hi;
            lo.h[0] = __floats2half2_rn(aclo[j].x * dd, aclo[j].y * dd);
            lo.h[1] = __floats2half2_rn(aclo[j].z * dd, aclo[j].w * dd);
            hi.h[0] = __floats2half2_rn(achi[j].x * dd, achi[j].y * dd);
            hi.h[1] = __floats2half2_rn(achi[j].z * dd, achi[j].w * dd);
            uint2* p = (uint2*)(xw2h + (size_t)rows[j] * OUT_DIM);
            p[tx] = lo.u;
            p[8 + tx] = hi.u;
        }
    }
}

// ---------------- Layer-2 aggregation FUSED with FC + leaky_relu ----------------
__global__ __launch_bounds__(256) void k_agg_final(const int* __restrict__ row_ptr,
                                                   const int* __restrict__ csr_src,
                                                   const float* __restrict__ dinv,
                                                   const __half* __restrict__ xwh,
                                                   const float* __restrict__ b2,
                                                   const float* __restrict__ Wfc,
                                                   const float* __restrict__ bfc,
                                                   float* __restrict__ out, int N) {
    constexpr int F = OUT_DIM;
    constexpr int L = F / 8;       // 8 lanes per row
    constexpr int EPW = 64 / L;    // 8 edge slots per wave
    __shared__ float wfs[OUT_DIM * 2];
    __shared__ float b2s[OUT_DIM];
    __shared__ float bfs[2];
    int tid = threadIdx.x;
    if (tid < 32) ((float4*)wfs)[tid] = ((const float4*)Wfc)[tid];
    else if (tid < 48) ((float4*)b2s)[tid - 32] = ((const float4*)b2)[tid - 32];
    else if (tid == 48) { bfs[0] = bfc[0]; bfs[1] = bfc[1]; }
    __syncthreads();
    int node = (blockIdx.x * 256 + tid) >> 6;
    if (node >= N) return;
    int lane = tid & 63;
    int sub = lane / L;
    int c   = lane % L;
    int beg = row_ptr[node], end = row_ptr[node + 1];
    float dd = dinv[node];
    uint4 us = *(const uint4*)(xwh + (size_t)node * F + c * 8);
    float a0 = 0.f, a1 = 0.f, a2 = 0.f, a3 = 0.f;
    float a4 = 0.f, a5 = 0.f, a6 = 0.f, a7 = 0.f;
    int j = beg + sub;
    for (; j + EPW < end; j += 2 * EPW) {
        int s0 = csr_src[j];
        int s1 = csr_src[j + EPW];
        uint4 u0 = *(const uint4*)(xwh + (size_t)s0 * F + c * 8);
        uint4 u1 = *(const uint4*)(xwh + (size_t)s1 * F + c * 8);
        float2 v0 = __half22float2(*(__half2*)&u0.x);
        float2 v1 = __half22float2(*(__half2*)&u0.y);
        float2 v2 = __half22float2(*(__half2*)&u0.z);
        float2 v3 = __half22float2(*(__half2*)&u0.w);
        a0 += v0.x; a1 += v0.y; a2 += v1.x; a3 += v1.y;
        a4 += v2.x; a5 += v2.y; a6 += v3.x; a7 += v3.y;
        v0 = __half22float2(*(__half2*)&u1.x);
        v1 = __half22float2(*(__half2*)&u1.y);
        v2 = __half22float2(*(__half2*)&u1.z);
        v3 = __half22float2(*(__half2*)&u1.w);
        a0 += v0.x; a1 += v0.y; a2 += v1.x; a3 += v1.y;
        a4 += v2.x; a5 += v2.y; a6 += v3.x; a7 += v3.y;
    }
    if (j < end) {
        int s = csr_src[j];
        uint4 u = *(const uint4*)(xwh + (size_t)s * F + c * 8);
        float2 v0 = __half22float2(*(__half2*)&u.x);
        float2 v1 = __half22float2(*(__half2*)&u.y);
        float2 v2 = __half22float2(*(__half2*)&u.z);
        float2 v3 = __half22float2(*(__half2*)&u.w);
        a0 += v0.x; a1 += v0.y; a2 += v1.x; a3 += v1.y;
        a4 += v2.x; a5 += v2.y; a6 += v3.x; a7 += v3.y;
    }
#pragma unroll
    for (int off = L; off < 64; off <<= 1) {
        a0 += __shfl_xor(a0, off); a1 += __shfl_xor(a1, off);
        a2 += __shfl_xor(a2, off); a3 += __shfl_xor(a3, off);
        a4 += __shfl_xor(a4, off); a5 += __shfl_xor(a5, off);
        a6 += __shfl_xor(a6, off); a7 += __shfl_xor(a7, off);
    }
    float2 v0 = __half22float2(*(__half2*)&us.x);
    float2 v1 = __half22float2(*(__half2*)&us.y);
    float2 v2 = __half22float2(*(__half2*)&us.z);
    float2 v3 = __half22float2(*(__half2*)&us.w);
    float h[8];
    h[0] = (a0 + v0.x) * dd; h[1] = (a1 + v0.y) * dd;
    h[2] = (a2 + v1.x) * dd; h[3] = (a3 + v1.y) * dd;
    h[4] = (a4 + v2.x) * dd; h[5] = (a5 + v2.y) * dd;
    h[6] = (a6 + v3.x) * dd; h[7] = (a7 + v3.y) * dd;
    float o0 = 0.f, o1 = 0.f;
#pragma unroll
    for (int k = 0; k < 8; ++k) {
        float hv = h[k] + b2s[c * 8 + k];
        o0 += hv * wfs[(c * 8 + k) * 2 + 0];
        o1 += hv * wfs[(c * 8 + k) * 2 + 1];
    }
#pragma unroll
    for (int off = 1; off < L; off <<= 1) {
        o0 += __shfl_xor(o0, off);
        o1 += __shfl_xor(o1, off);
    }
    if (lane == 0) {
        o0 += bfs[0]; o1 += bfs[1];
        float2 r;
        r.x = o0 > 0.f ? o0 : 0.01f * o0;
        r.y = o1 > 0.f ? o1 : 0.01f * o1;
        *(float2*)(out + (size_t)node * 2) = r;
    }
}

extern "C" void kernel_launch(void* const* d_in, const int* in_sizes, int n_in,
                              void* d_out, int out_size, void* d_ws, size_t ws_size,
                              hipStream_t stream) {
    const float* x   = (const float*)d_in[0];
    const int*   ei  = (const int*)d_in[1];
    const float* W1  = (const float*)d_in[2];
    const float* b1  = (const float*)d_in[3];
    const float* W2  = (const float*)d_in[4];
    const float* b2  = (const float*)d_in[5];
    const float* Wfc = (const float*)d_in[6];
    const float* bfc = (const float*)d_in[7];

    const int N = in_sizes[0] / IN_DIM;   // 50000
    const int E = in_sizes[1] / 2;        // 800000
    const int* src = ei;
    const int* dst = ei + E;
    const int nbin = (N + BINW - 1) / BINW;  // 391

    // Workspace layout (256B-aligned regions), all << ws_size:
    char* base = (char*)d_ws;
    size_t off = 0;
    auto take = [&](size_t bytes) { size_t o = off; off = (off + bytes + 255) & ~(size_t)255; return (void*)(base + o); };
    int*    row_ptr  = (int*)take((size_t)(N + 1) * 4);
    int*    csr_src  = (int*)take((size_t)E * 4);
    int*    hist     = (int*)take((size_t)nbin * EBLK * 4);
    int*    total    = (int*)take((size_t)nbin * 4);
    int*    bin_base = (int*)take((size_t)(nbin + 1) * 4);
    unsigned int* ebin = (unsigned int*)take((size_t)E * 4);
    float*  dinv     = (float*)take((size_t)N * 4);
    __half* xw1h     = (__half*)take((size_t)N * HID_DIM * 2);   // layer-1 messages
    __half* xr1h     = (__half*)take((size_t)N * HID_DIM * 2);   // relu(agg1+b1)
    __half* xw2h     = (__half*)take((size_t)N * OUT_DIM * 2);   // layer-2 messages

    // CSR build (no memsets needed — every array fully written before read)
    k_bin_hist<<<EBLK, 256, 0, stream>>>(dst, hist, E, nbin);
    k_bin_scan<<<nbin, 256, 0, stream>>>(hist, total);
    k_bin_base<<<1, 256, 0, stream>>>(total, bin_base, nbin);
    k_bin_scatter<<<EBLK, 256, 0, stream>>>(src, dst, hist, bin_base, ebin, E, nbin);
    k_bin_fill<<<nbin, 256, 0, stream>>>(ebin, bin_base, row_ptr, csr_src, dinv, N, nbin);

    const int nTile = (N + 127) / 128;

    // Layer 1
    k_gemm1<<<nTile, 256, 0, stream>>>(x, W1, dinv, xw1h, N);
    k_agg1<<<(N + 3) / 4, 256, 0, stream>>>(row_ptr, csr_src, dinv, xw1h, b1, xr1h, N);

    // Layer 2 (A already relu+bias fp16; FC + leaky fused into agg)
    k_gemm2<<<nTile, 256, 0, stream>>>(xr1h, W2, dinv, xw2h, N);
    k_agg_final<<<(N + 3) / 4, 256, 0, stream>>>(row_ptr, csr_src, dinv, xw2h,
                                                 b2, Wfc, bfc, (float*)d_out, N);
}

// Round 8
// 180.298 us; speedup vs baseline: 12.1261x; 1.1764x over previous
//
#include <hip/hip_runtime.h>
#include <hip/hip_fp16.h>

// Problem constants (from reference): N=50000, E=800000, dims 128->128->64->2.
#define IN_DIM 128
#define HID_DIM 128
#define OUT_DIM 64
#define BINW 128          // nodes per bin (dst >> 7)
#define BINSHIFT 7
#define MAXBIN 512        // LDS capacity bound; nbin = ceil(N/128) = 391 for N=50000
#define EBLK 256          // blocks in edge passes

// ---------------- P1: per-block bin histogram ----------------
__global__ __launch_bounds__(256) void k_bin_hist(const int* __restrict__ dst,
                                                  int* __restrict__ hist, int E, int nbin) {
    __shared__ int h[MAXBIN];
    int tid = threadIdx.x;
    for (int k = tid; k < nbin; k += 256) h[k] = 0;
    __syncthreads();
    int per = E / gridDim.x;
    int base = blockIdx.x * per;
    int end = (blockIdx.x + 1 == gridDim.x) ? E : base + per;
    for (int i = base + tid; i < end; i += 256)
        atomicAdd(&h[dst[i] >> BINSHIFT], 1);
    __syncthreads();
    for (int k = tid; k < nbin; k += 256) hist[k * EBLK + blockIdx.x] = h[k];
}

// ---------------- P2a: scan each bin's 256 per-block counts ----------------
__global__ __launch_bounds__(256) void k_bin_scan(int* __restrict__ hist,
                                                  int* __restrict__ total) {
    __shared__ int part[256];
    int k = blockIdx.x;
    int t = threadIdx.x;
    int v = hist[k * EBLK + t];
    part[t] = v;
    __syncthreads();
    for (int off = 1; off < 256; off <<= 1) {
        int u = (t >= off) ? part[t - off] : 0;
        __syncthreads();
        part[t] += u;
        __syncthreads();
    }
    hist[k * EBLK + t] = part[t] - v;  // exclusive within bin
    if (t == 255) total[k] = part[255];
}

// ---------------- P2b: exclusive scan of bin totals ----------------
__global__ __launch_bounds__(256) void k_bin_base(const int* __restrict__ total,
                                                  int* __restrict__ bin_base, int nbin) {
    __shared__ int part[256];
    int t = threadIdx.x;
    int carry = 0;
    for (int base = 0; base < nbin; base += 256) {
        int i = base + t;
        int v = (i < nbin) ? total[i] : 0;
        part[t] = v;
        __syncthreads();
        for (int off = 1; off < 256; off <<= 1) {
            int u = (t >= off) ? part[t - off] : 0;
            __syncthreads();
            part[t] += u;
            __syncthreads();
        }
        if (i < nbin) bin_base[i] = carry + part[t] - v;
        carry += part[255];
        __syncthreads();
    }
    if (t == 0) bin_base[nbin] = carry;  // == E
}

// ---------------- P3: scatter packed edges into bin segments ----------------
__global__ __launch_bounds__(256) void k_bin_scatter(const int* __restrict__ src,
                                                     const int* __restrict__ dst,
                                                     const int* __restrict__ hist,
                                                     const int* __restrict__ bin_base,
                                                     unsigned int* __restrict__ ebin,
                                                     int E, int nbin) {
    __shared__ int off[MAXBIN];
    int tid = threadIdx.x;
    for (int k = tid; k < nbin; k += 256)
        off[k] = bin_base[k] + hist[k * EBLK + blockIdx.x];
    __syncthreads();
    int per = E / gridDim.x;
    int base = blockIdx.x * per;
    int end = (blockIdx.x + 1 == gridDim.x) ? E : base + per;
    for (int i = base + tid; i < end; i += 256) {
        unsigned int s = (unsigned int)src[i];
        unsigned int d = (unsigned int)dst[i];
        int pos = atomicAdd(&off[d >> BINSHIFT], 1);
        ebin[pos] = s | (d << 16);
    }
}

// ---------------- P4: per-bin fine fill — row_ptr, dinv, csr_src ----------------
__global__ __launch_bounds__(256) void k_bin_fill(const unsigned int* __restrict__ ebin,
                                                  const int* __restrict__ bin_base,
                                                  int* __restrict__ row_ptr,
                                                  int* __restrict__ csr_src,
                                                  float* __restrict__ dinv, int N, int nbin) {
    __shared__ int cnt[BINW];
    __shared__ int excl[BINW];
    __shared__ int start[BINW];
    int k = blockIdx.x;
    int node0 = k * BINW;
    int nn = min(BINW, N - node0);
    int t = threadIdx.x;
    if (t < BINW) cnt[t] = 0;
    __syncthreads();
    int eb = bin_base[k], ee = bin_base[k + 1];
    for (int i = eb + t; i < ee; i += 256)
        atomicAdd(&cnt[(ebin[i] >> 16) - node0], 1);
    __syncthreads();
    if (t < BINW) excl[t] = (t < nn) ? cnt[t] : 0;
    __syncthreads();
    for (int off = 1; off < BINW; off <<= 1) {
        int u = 0;
        if (t < BINW && t >= off) u = excl[t - off];
        __syncthreads();
        if (t < BINW) excl[t] += u;   // inclusive scan
        __syncthreads();
    }
    if (t < nn) {
        int deg = cnt[t];
        int e0 = eb + excl[t] - deg;  // exclusive
        start[t] = e0;
        row_ptr[node0 + t] = e0;
        dinv[node0 + t] = rsqrtf((float)deg + 1.0f);
        cnt[t] = 0;                   // reuse as fill counter
    }
    if (k == nbin - 1 && t == 0) row_ptr[N] = ee;
    __syncthreads();
    for (int i = eb + t; i < ee; i += 256) {
        unsigned int e = ebin[i];
        int s = (int)(e & 0xffffu);
        int dl = (int)(e >> 16) - node0;
        int slot = start[dl] + atomicAdd(&cnt[dl], 1);
        csr_src[slot] = s;
    }
}

// ---------------- Wc = W2 @ Wfc (128x2), bc = b2 @ Wfc + bfc ----------------
__global__ __launch_bounds__(256) void k_wc(const float* __restrict__ W2,
                                            const float* __restrict__ Wfc,
                                            const float* __restrict__ b2,
                                            const float* __restrict__ bfc,
                                            float* __restrict__ Wc,
                                            float* __restrict__ bc) {
    int t = threadIdx.x;
    int k = t >> 1, j = t & 1;
    float acc = 0.f;
#pragma unroll 8
    for (int m = 0; m < OUT_DIM; ++m) acc += W2[k * OUT_DIM + m] * Wfc[m * 2 + j];
    Wc[k * 2 + j] = acc;
    if (k == 0) {
        float b = 0.f;
#pragma unroll 8
        for (int m = 0; m < OUT_DIM; ++m) b += b2[m] * Wfc[m * 2 + j];
        bc[j] = b + bfc[j];
    }
}

// ---------------- GEMM1: xw1h = fp16(dinv[row] * (x @ W1)) ----------------
// Block tile 128x128, 256 threads, 8 rows x 8 cols per thread. A from global
// (16-lane broadcast). LDS = W only (64 KB) -> 2 blocks/CU.
__global__ __launch_bounds__(256) void k_gemm1(const float* __restrict__ x,
                                               const float* __restrict__ W,
                                               const float* __restrict__ dinv,
                                               __half* __restrict__ xwh, int N) {
    __shared__ float Ws[128][128];   // [k][col]
    int tid = threadIdx.x;
    const float4* W4 = (const float4*)W;
    float4* Ws4 = (float4*)&Ws[0][0];
#pragma unroll
    for (int i = 0; i < 16; ++i) Ws4[tid + 256 * i] = W4[tid + 256 * i];
    __syncthreads();
    int tx = tid & 15, ty = tid >> 4;
    int row0 = blockIdx.x * 128;
    int rows[8];
    const float* xr[8];
#pragma unroll
    for (int j = 0; j < 8; ++j) {
        int row = row0 + ty + 16 * j;
        rows[j] = row;
        if (row > N - 1) row = N - 1;
        xr[j] = x + (size_t)row * IN_DIM;
    }
    float4 aclo[8], achi[8];
#pragma unroll
    for (int j = 0; j < 8; ++j) {
        aclo[j] = make_float4(0.f, 0.f, 0.f, 0.f);
        achi[j] = make_float4(0.f, 0.f, 0.f, 0.f);
    }
#pragma unroll 2
    for (int k4 = 0; k4 < 32; ++k4) {
        float4 av[8];
#pragma unroll
        for (int j = 0; j < 8; ++j) av[j] = *(const float4*)(xr[j] + k4 * 4);
#pragma unroll
        for (int kk = 0; kk < 4; ++kk) {
            float4 blo = *(const float4*)&Ws[k4 * 4 + kk][4 * tx];
            float4 bhi = *(const float4*)&Ws[k4 * 4 + kk][64 + 4 * tx];
#pragma unroll
            for (int j = 0; j < 8; ++j) {
                float a = (kk == 0) ? av[j].x : (kk == 1) ? av[j].y : (kk == 2) ? av[j].z : av[j].w;
                aclo[j].x += a * blo.x; aclo[j].y += a * blo.y;
                aclo[j].z += a * blo.z; aclo[j].w += a * blo.w;
                achi[j].x += a * bhi.x; achi[j].y += a * bhi.y;
                achi[j].z += a * bhi.z; achi[j].w += a * bhi.w;
            }
        }
    }
#pragma unroll
    for (int j = 0; j < 8; ++j) {
        if (rows[j] < N) {
            float dd = dinv[rows[j]];
            union { __half2 h[2]; uint2 u; } lo, hi;
            lo.h[0] = __floats2half2_rn(aclo[j].x * dd, aclo[j].y * dd);
            lo.h[1] = __floats2half2_rn(aclo[j].z * dd, aclo[j].w * dd);
            hi.h[0] = __floats2half2_rn(achi[j].x * dd, achi[j].y * dd);
            hi.h[1] = __floats2half2_rn(achi[j].z * dd, achi[j].w * dd);
            uint2* p = (uint2*)(xwh + (size_t)rows[j] * HID_DIM);
            p[tx] = lo.u;
            p[16 + tx] = hi.u;
        }
    }
}

// ---------------- Layer-1 aggregation + bias + ReLU + (h1 @ Wc) epilogue ----------------
// h1 = relu(dinv[d]*(sum_s xwh[s] + xwh[d]) + b1)   (xwh pre-scaled by dinv)
// z[d] = dinv[d] * (h1 @ Wc)    -- only 2 floats written per node!
// One wave per node, 16 lanes/row, 2x-unrolled gather.
__global__ __launch_bounds__(256) void k_agg1z(const int* __restrict__ row_ptr,
                                               const int* __restrict__ csr_src,
                                               const float* __restrict__ dinv,
                                               const __half* __restrict__ xwh,
                                               const float* __restrict__ b1,
                                               const float* __restrict__ Wc,
                                               float* __restrict__ z, int N) {
    constexpr int F = HID_DIM;
    constexpr int L = F / 8;       // 16 lanes per row, 16B/lane
    constexpr int EPW = 64 / L;    // 4 edge slots per wave
    __shared__ float Wcs[HID_DIM * 2];
    int tid = threadIdx.x;
    if (tid < 64) ((float4*)Wcs)[tid] = ((const float4*)Wc)[tid];
    __syncthreads();
    int node = (blockIdx.x * 256 + tid) >> 6;
    if (node >= N) return;
    int lane = tid & 63;
    int sub = lane / L;
    int c   = lane % L;
    int beg = row_ptr[node], end = row_ptr[node + 1];
    // hoisted loads (overlap with gather)
    float dd = dinv[node];
    uint4 us = *(const uint4*)(xwh + (size_t)node * F + c * 8);
    float4 b1a = *(const float4*)(b1 + c * 8);
    float4 b1b = *(const float4*)(b1 + c * 8 + 4);
    float a0 = 0.f, a1 = 0.f, a2 = 0.f, a3 = 0.f;
    float a4 = 0.f, a5 = 0.f, a6 = 0.f, a7 = 0.f;
    int j = beg + sub;
    for (; j + EPW < end; j += 2 * EPW) {
        int s0 = csr_src[j];
        int s1 = csr_src[j + EPW];
        uint4 u0 = *(const uint4*)(xwh + (size_t)s0 * F + c * 8);
        uint4 u1 = *(const uint4*)(xwh + (size_t)s1 * F + c * 8);
        float2 v0 = __half22float2(*(__half2*)&u0.x);
        float2 v1 = __half22float2(*(__half2*)&u0.y);
        float2 v2 = __half22float2(*(__half2*)&u0.z);
        float2 v3 = __half22float2(*(__half2*)&u0.w);
        a0 += v0.x; a1 += v0.y; a2 += v1.x; a3 += v1.y;
        a4 += v2.x; a5 += v2.y; a6 += v3.x; a7 += v3.y;
        v0 = __half22float2(*(__half2*)&u1.x);
        v1 = __half22float2(*(__half2*)&u1.y);
        v2 = __half22float2(*(__half2*)&u1.z);
        v3 = __half22float2(*(__half2*)&u1.w);
        a0 += v0.x; a1 += v0.y; a2 += v1.x; a3 += v1.y;
        a4 += v2.x; a5 += v2.y; a6 += v3.x; a7 += v3.y;
    }
    if (j < end) {
        int s = csr_src[j];
        uint4 u = *(const uint4*)(xwh + (size_t)s * F + c * 8);
        float2 v0 = __half22float2(*(__half2*)&u.x);
        float2 v1 = __half22float2(*(__half2*)&u.y);
        float2 v2 = __half22float2(*(__half2*)&u.z);
        float2 v3 = __half22float2(*(__half2*)&u.w);
        a0 += v0.x; a1 += v0.y; a2 += v1.x; a3 += v1.y;
        a4 += v2.x; a5 += v2.y; a6 += v3.x; a7 += v3.y;
    }
#pragma unroll
    for (int off = L; off < 64; off <<= 1) {
        a0 += __shfl_xor(a0, off); a1 += __shfl_xor(a1, off);
        a2 += __shfl_xor(a2, off); a3 += __shfl_xor(a3, off);
        a4 += __shfl_xor(a4, off); a5 += __shfl_xor(a5, off);
        a6 += __shfl_xor(a6, off); a7 += __shfl_xor(a7, off);
    }
    // all lanes now hold the full column sums for their c
    float2 v0 = __half22float2(*(__half2*)&us.x);
    float2 v1 = __half22float2(*(__half2*)&us.y);
    float2 v2 = __half22float2(*(__half2*)&us.z);
    float2 v3 = __half22float2(*(__half2*)&us.w);
    float h[8];
    h[0] = fmaxf((a0 + v0.x) * dd + b1a.x, 0.f);
    h[1] = fmaxf((a1 + v0.y) * dd + b1a.y, 0.f);
    h[2] = fmaxf((a2 + v1.x) * dd + b1a.z, 0.f);
    h[3] = fmaxf((a3 + v1.y) * dd + b1a.w, 0.f);
    h[4] = fmaxf((a4 + v2.x) * dd + b1b.x, 0.f);
    h[5] = fmaxf((a5 + v2.y) * dd + b1b.y, 0.f);
    h[6] = fmaxf((a6 + v3.x) * dd + b1b.z, 0.f);
    h[7] = fmaxf((a7 + v3.y) * dd + b1b.w, 0.f);
    float o0 = 0.f, o1 = 0.f;
#pragma unroll
    for (int k = 0; k < 8; ++k) {
        o0 += h[k] * Wcs[(c * 8 + k) * 2 + 0];
        o1 += h[k] * Wcs[(c * 8 + k) * 2 + 1];
    }
    // reduce the 16 c-lanes (xor<16 stays within each 16-lane group)
#pragma unroll
    for (int off = 1; off < L; off <<= 1) {
        o0 += __shfl_xor(o0, off);
        o1 += __shfl_xor(o1, off);
    }
    if (lane == 0) {
        float2 r; r.x = o0 * dd; r.y = o1 * dd;
        *(float2*)(z + (size_t)node * 2) = r;
    }
}

// ---------------- Layer-2 aggregation on z (2 floats/node) + bias + leaky ----------------
// out[d] = leaky( dinv[d]*(sum_s z[s] + z[d]) + bc )
// 8 lanes per node; z table is 400 KB -> L2-resident.
__global__ __launch_bounds__(256) void k_agg2(const int* __restrict__ row_ptr,
                                              const int* __restrict__ csr_src,
                                              const float* __restrict__ dinv,
                                              const float* __restrict__ z,
                                              const float* __restrict__ bc,
                                              float* __restrict__ out, int N) {
    int tid = threadIdx.x;
    int gwave = (blockIdx.x * 256 + tid) >> 6;
    int lane = tid & 63;
    int grp = lane >> 3, li = lane & 7;
    int node = gwave * 8 + grp;
    if (node >= N) return;
    int beg = row_ptr[node], end = row_ptr[node + 1];
    float s0 = 0.f, s1 = 0.f;
    int j = beg + li;
    for (; j + 8 < end; j += 16) {
        int sa = csr_src[j];
        int sb = csr_src[j + 8];
        float2 za = *(const float2*)(z + (size_t)sa * 2);
        float2 zb = *(const float2*)(z + (size_t)sb * 2);
        s0 += za.x + zb.x; s1 += za.y + zb.y;
    }
    if (j < end) {
        int s = csr_src[j];
        float2 zv = *(const float2*)(z + (size_t)s * 2);
        s0 += zv.x; s1 += zv.y;
    }
#pragma unroll
    for (int off = 1; off < 8; off <<= 1) {
        s0 += __shfl_xor(s0, off);
        s1 += __shfl_xor(s1, off);
    }
    if (li == 0) {
        float2 zs = *(const float2*)(z + (size_t)node * 2);
        float dd = dinv[node];
        float o0 = (s0 + zs.x) * dd + bc[0];
        float o1 = (s1 + zs.y) * dd + bc[1];
        float2 r;
        r.x = o0 > 0.f ? o0 : 0.01f * o0;
        r.y = o1 > 0.f ? o1 : 0.01f * o1;
        *(float2*)(out + (size_t)node * 2) = r;
    }
}

extern "C" void kernel_launch(void* const* d_in, const int* in_sizes, int n_in,
                              void* d_out, int out_size, void* d_ws, size_t ws_size,
                              hipStream_t stream) {
    const float* x   = (const float*)d_in[0];
    const int*   ei  = (const int*)d_in[1];
    const float* W1  = (const float*)d_in[2];
    const float* b1  = (const float*)d_in[3];
    const float* W2  = (const float*)d_in[4];
    const float* b2  = (const float*)d_in[5];
    const float* Wfc = (const float*)d_in[6];
    const float* bfc = (const float*)d_in[7];

    const int N = in_sizes[0] / IN_DIM;   // 50000
    const int E = in_sizes[1] / 2;        // 800000
    const int* src = ei;
    const int* dst = ei + E;
    const int nbin = (N + BINW - 1) / BINW;  // 391

    // Workspace layout (256B-aligned regions):
    char* base = (char*)d_ws;
    size_t off = 0;
    auto take = [&](size_t bytes) { size_t o = off; off = (off + bytes + 255) & ~(size_t)255; return (void*)(base + o); };
    int*    row_ptr  = (int*)take((size_t)(N + 1) * 4);
    int*    csr_src  = (int*)take((size_t)E * 4);
    int*    hist     = (int*)take((size_t)nbin * EBLK * 4);
    int*    total    = (int*)take((size_t)nbin * 4);
    int*    bin_base = (int*)take((size_t)(nbin + 1) * 4);
    unsigned int* ebin = (unsigned int*)take((size_t)E * 4);
    float*  dinv     = (float*)take((size_t)N * 4);
    __half* xw1h     = (__half*)take((size_t)N * HID_DIM * 2);   // layer-1 messages
    float*  zbuf     = (float*)take((size_t)N * 2 * 4);          // z = dinv*(h1@Wc)
    float*  Wc       = (float*)take((size_t)HID_DIM * 2 * 4);
    float*  bc       = (float*)take(2 * 4);

    // CSR build (no memsets needed — every array fully written before read)
    k_bin_hist<<<EBLK, 256, 0, stream>>>(dst, hist, E, nbin);
    k_bin_scan<<<nbin, 256, 0, stream>>>(hist, total);
    k_bin_base<<<1, 256, 0, stream>>>(total, bin_base, nbin);
    k_bin_scatter<<<EBLK, 256, 0, stream>>>(src, dst, hist, bin_base, ebin, E, nbin);
    k_bin_fill<<<nbin, 256, 0, stream>>>(ebin, bin_base, row_ptr, csr_src, dinv, N, nbin);

    // Fold W2@Wfc (128x2) + bias constant
    k_wc<<<1, 256, 0, stream>>>(W2, Wfc, b2, bfc, Wc, bc);

    const int nTile = (N + 127) / 128;

    // Layer 1 GEMM
    k_gemm1<<<nTile, 256, 0, stream>>>(x, W1, dinv, xw1h, N);
    // Layer-1 aggregation + relu + folded 128x2 GEMV -> z
    k_agg1z<<<(N + 3) / 4, 256, 0, stream>>>(row_ptr, csr_src, dinv, xw1h, b1, Wc, zbuf, N);
    // Layer-2 aggregation on z + bias + leaky -> out
    const int nAgg2 = ((N + 7) / 8 * 64 + 255) / 256;
    k_agg2<<<nAgg2, 256, 0, stream>>>(row_ptr, csr_src, dinv, zbuf, bc, (float*)d_out, N);
}